// Round 2
// baseline (373.921 us; speedup 1.0000x reference)
//
#include <hip/hip_runtime.h>
#include <hip/hip_bf16.h>

// Problem constants
constexpr int BB = 4;
constexpr int TT = 1024;
constexpr int DD = 512;
constexpr int PP = 64;
constexpr int MM = 256;

// Pre-scale factor: exp(2x) = exp2(CSCALE * x). Producers write h*CSCALE so the
// scores inner loop is add -> v_exp -> add -> v_rcp -> fma (no extra mul).
constexpr float CSCALE = 2.8853900817779268f; // 2 * log2(e)

// Kernel 1: w1hs = (inputs@W1 + b1)*CSCALE ; w2hs = (inputs@W2 + b2)*CSCALE
// 512 blocks x 256 threads; each thread computes 2 rows for one p -> W loads reused 2x.
__global__ __launch_bounds__(256) void proj_kernel(
    const float* __restrict__ x, const float* __restrict__ W1, const float* __restrict__ b1,
    const float* __restrict__ W2, const float* __restrict__ b2,
    float* __restrict__ w1hs, float* __restrict__ w2hs) {
    int tid = threadIdx.x;
    int p = tid & 63;
    int rr = tid >> 6;                          // 0..3
    int row0 = (blockIdx.x << 3) + (rr << 1);   // 8 rows per block, 2 per thread
    const float* xr0 = x + (size_t)row0 * DD;
    const float* xr1 = xr0 + DD;
    float a10 = b1[p], a11 = b1[p];
    float a20 = b2[p], a21 = b2[p];
    #pragma unroll 4
    for (int d = 0; d < DD; d++) {
        float wv1 = W1[d * PP + p];
        float wv2 = W2[d * PP + p];
        float x0 = xr0[d];
        float x1 = xr1[d];
        a10 = fmaf(x0, wv1, a10);
        a11 = fmaf(x1, wv1, a11);
        a20 = fmaf(x0, wv2, a20);
        a21 = fmaf(x1, wv2, a21);
    }
    w1hs[(size_t)row0 * PP + p]        = a10 * CSCALE;
    w1hs[(size_t)(row0 + 1) * PP + p]  = a11 * CSCALE;
    w2hs[(size_t)row0 * PP + p]        = a20 * CSCALE;
    w2hs[(size_t)(row0 + 1) * PP + p]  = a21 * CSCALE;
}

// Kernel 2: w3es = (ec@W3 + b3)*CSCALE   (B x P = 4 x 64 outputs)
__global__ __launch_bounds__(256) void ec_proj_kernel(
    const float* __restrict__ ec, const float* __restrict__ W3,
    const float* __restrict__ b3, float* __restrict__ w3es) {
    int tid = threadIdx.x;
    int b = tid >> 6, p = tid & 63;
    float a = b3[p];
    const float* e = ec + (size_t)b * MM;
    #pragma unroll 4
    for (int m = 0; m < MM; m++) a = fmaf(e[m], W3[m * PP + p], a);
    w3es[b * PP + p] = a * CSCALE;
}

// Accumulate 4 elements of sum((-2*waw) * rcp(exp2(h+w)+1)) into acc.
__device__ __forceinline__ float acc4(float acc, float4 w, const float* __restrict__ hp,
                                      const float* __restrict__ wp) {
    acc = fmaf(wp[0], __builtin_amdgcn_rcpf(__builtin_amdgcn_exp2f(hp[0] + w.x) + 1.0f), acc);
    acc = fmaf(wp[1], __builtin_amdgcn_rcpf(__builtin_amdgcn_exp2f(hp[1] + w.y) + 1.0f), acc);
    acc = fmaf(wp[2], __builtin_amdgcn_rcpf(__builtin_amdgcn_exp2f(hp[2] + w.z) + 1.0f), acc);
    acc = fmaf(wp[3], __builtin_amdgcn_rcpf(__builtin_amdgcn_exp2f(hp[3] + w.w) + 1.0f), acc);
    return acc;
}

// Kernel 3: one block per (b,t). score(u) = wa_b + sum_p waw_p*tanh(h_p + w2h[u]_p)
//         = (wa_b + sum waw) + sum_p (-2 waw_p) / (exp2(hs_p + ws_p) + 1)
// then softmax over u, write normalized row of at.
__global__ __launch_bounds__(256) void scores_kernel(
    const float* __restrict__ w1hs, const float* __restrict__ w2hs,
    const float* __restrict__ w3es, const float* __restrict__ wa_w,
    const float* __restrict__ wa_b, float* __restrict__ at) {
    __shared__ float hs[PP];
    __shared__ float ww2[PP];
    __shared__ float red[4];
    __shared__ float sbase;
    int tid = threadIdx.x;
    int bt = blockIdx.x;              // b*T + t
    int b = bt >> 10;
    if (tid < PP) {
        hs[tid] = w1hs[(size_t)bt * PP + tid] + w3es[b * PP + tid];
        float w = wa_w[tid];
        ww2[tid] = -2.0f * w;
        float s = w;
        #pragma unroll
        for (int off = 32; off > 0; off >>= 1) s += __shfl_xor(s, off, 64);
        if (tid == 0) sbase = s + wa_b[0];
    }
    __syncthreads();
    float base = sbase;

    float sc[4];
    float lmax = -1e30f;
    #pragma unroll
    for (int k = 0; k < 4; k++) {
        int u = (k << 8) + tid;
        const float4* wrow = (const float4*)(w2hs + ((size_t)(b << 10) + u) * PP);
        // 4 independent accumulation chains; loads batched 4 float4 at a time.
        float pa0 = 0.0f, pa1 = 0.0f, pa2 = 0.0f, pa3 = 0.0f;
        #pragma unroll
        for (int g = 0; g < 4; g++) {
            float4 r0 = wrow[(g << 2) + 0];
            float4 r1 = wrow[(g << 2) + 1];
            float4 r2 = wrow[(g << 2) + 2];
            float4 r3 = wrow[(g << 2) + 3];
            pa0 = acc4(pa0, r0, &hs[(g << 4) + 0],  &ww2[(g << 4) + 0]);
            pa1 = acc4(pa1, r1, &hs[(g << 4) + 4],  &ww2[(g << 4) + 4]);
            pa2 = acc4(pa2, r2, &hs[(g << 4) + 8],  &ww2[(g << 4) + 8]);
            pa3 = acc4(pa3, r3, &hs[(g << 4) + 12], &ww2[(g << 4) + 12]);
        }
        float acc = base + ((pa0 + pa1) + (pa2 + pa3));
        sc[k] = acc;
        lmax = fmaxf(lmax, acc);
    }
    // block max
    #pragma unroll
    for (int off = 32; off > 0; off >>= 1) lmax = fmaxf(lmax, __shfl_xor(lmax, off, 64));
    if ((tid & 63) == 0) red[tid >> 6] = lmax;
    __syncthreads();
    float mx = fmaxf(fmaxf(red[0], red[1]), fmaxf(red[2], red[3]));

    float lsum = 0.0f;
    #pragma unroll
    for (int k = 0; k < 4; k++) {
        float e = __expf(sc[k] - mx);
        sc[k] = e;
        lsum += e;
    }
    #pragma unroll
    for (int off = 32; off > 0; off >>= 1) lsum += __shfl_xor(lsum, off, 64);
    __syncthreads();                   // protect red reuse
    if ((tid & 63) == 0) red[tid >> 6] = lsum;
    __syncthreads();
    float inv = 1.0f / (red[0] + red[1] + red[2] + red[3]);

    float* arow = at + (size_t)bt * TT;
    #pragma unroll
    for (int k = 0; k < 4; k++) {
        arow[(k << 8) + tid] = sc[k] * inv;
    }
}

// Kernel 4: out[b] = at[b] (1024x1024) @ inputs[b] (1024x512), fp32 tiled GEMM.
// BM=BN=64, BK=32, 256 threads, 4x4 micro-tile per thread.
// As is stored k-major (As[k][m]) so fragment reads are clean float4s.
// All accumulators are explicit scalars (previous round: c[4][4] + address-of
// float4 locals -> scratch demotion, VGPR_Count=36, 30 ms dispatch).
__global__ __launch_bounds__(256) void av_gemm_kernel(
    const float* __restrict__ at, const float* __restrict__ x, float* __restrict__ out) {
    __shared__ float As[32][68];   // [k][m], pad 64->68 keeps 16B align, breaks pow2 stride
    __shared__ float Bs[32][68];   // [k][n]
    int b = blockIdx.z;
    int tm = blockIdx.y << 6;
    int tn = blockIdx.x << 6;
    const float* A = at + (size_t)b * TT * TT;
    const float* X = x + (size_t)b * TT * DD;
    float* C = out + (size_t)b * TT * DD;
    int tid = threadIdx.x;
    int tx = tid & 15, ty = tid >> 4;

    float c00 = 0.f, c01 = 0.f, c02 = 0.f, c03 = 0.f;
    float c10 = 0.f, c11 = 0.f, c12 = 0.f, c13 = 0.f;
    float c20 = 0.f, c21 = 0.f, c22 = 0.f, c23 = 0.f;
    float c30 = 0.f, c31 = 0.f, c32 = 0.f, c33 = 0.f;

    for (int k0 = 0; k0 < TT; k0 += 32) {
        #pragma unroll
        for (int i = 0; i < 2; i++) {
            int f = tid + (i << 8);            // 0..511
            int m = f >> 3, kq = (f & 7) << 2; // A tile: 64 rows x 32 k, float4 along k
            float4 av = *(const float4*)(A + (size_t)(tm + m) * TT + k0 + kq);
            As[kq + 0][m] = av.x;
            As[kq + 1][m] = av.y;
            As[kq + 2][m] = av.z;
            As[kq + 3][m] = av.w;
            int rB = f >> 4, cB = (f & 15) << 2; // B tile: 32 k x 64 n
            float4 bv = *(const float4*)(X + (size_t)(k0 + rB) * DD + tn + cB);
            *(float4*)&Bs[rB][cB] = bv;
        }
        __syncthreads();
        #pragma unroll
        for (int kk = 0; kk < 32; kk++) {
            float4 a = *(const float4*)&As[kk][ty << 2];
            float4 v = *(const float4*)&Bs[kk][tx << 2];
            c00 = fmaf(a.x, v.x, c00); c01 = fmaf(a.x, v.y, c01);
            c02 = fmaf(a.x, v.z, c02); c03 = fmaf(a.x, v.w, c03);
            c10 = fmaf(a.y, v.x, c10); c11 = fmaf(a.y, v.y, c11);
            c12 = fmaf(a.y, v.z, c12); c13 = fmaf(a.y, v.w, c13);
            c20 = fmaf(a.z, v.x, c20); c21 = fmaf(a.z, v.y, c21);
            c22 = fmaf(a.z, v.z, c22); c23 = fmaf(a.z, v.w, c23);
            c30 = fmaf(a.w, v.x, c30); c31 = fmaf(a.w, v.y, c31);
            c32 = fmaf(a.w, v.z, c32); c33 = fmaf(a.w, v.w, c33);
        }
        __syncthreads();
    }
    size_t rbase = (size_t)(tm + (ty << 2)) * DD + tn + (tx << 2);
    *(float4*)(C + rbase)          = make_float4(c00, c01, c02, c03);
    *(float4*)(C + rbase + DD)     = make_float4(c10, c11, c12, c13);
    *(float4*)(C + rbase + 2 * DD) = make_float4(c20, c21, c22, c23);
    *(float4*)(C + rbase + 3 * DD) = make_float4(c30, c31, c32, c33);
}

extern "C" void kernel_launch(void* const* d_in, const int* in_sizes, int n_in,
                              void* d_out, int out_size, void* d_ws, size_t ws_size,
                              hipStream_t stream) {
    const float* inputs = (const float*)d_in[0];   // (B,T,D)
    const float* ec     = (const float*)d_in[1];   // (B,M)
    const float* W1     = (const float*)d_in[2];   // (D,P)
    const float* b1     = (const float*)d_in[3];   // (P,)
    const float* W2     = (const float*)d_in[4];   // (D,P)
    const float* b2     = (const float*)d_in[5];   // (P,)
    const float* W3     = (const float*)d_in[6];   // (M,P)
    const float* b3     = (const float*)d_in[7];   // (P,)
    const float* wa_w   = (const float*)d_in[8];   // (P,)
    const float* wa_b   = (const float*)d_in[9];   // scalar
    float* out = (float*)d_out;                    // (B,T,D) fp32

    // Workspace layout (floats): w1hs[262144] | w2hs[262144] | w3es[256] | pad | at[4194304]
    float* ws   = (float*)d_ws;
    float* w1hs = ws;
    float* w2hs = ws + 262144;
    float* w3es = ws + 524288;
    float* at   = ws + 524800;   // 16B-aligned offset; total ~18.9 MB

    hipLaunchKernelGGL(proj_kernel, dim3(512), dim3(256), 0, stream,
                       inputs, W1, b1, W2, b2, w1hs, w2hs);
    hipLaunchKernelGGL(ec_proj_kernel, dim3(1), dim3(256), 0, stream,
                       ec, W3, b3, w3es);
    hipLaunchKernelGGL(scores_kernel, dim3(BB * TT), dim3(256), 0, stream,
                       w1hs, w2hs, w3es, wa_w, wa_b, at);
    hipLaunchKernelGGL(av_gemm_kernel, dim3(DD / 64, TT / 64, BB), dim3(256), 0, stream,
                       at, inputs, out);
}

// Round 3
// 230.242 us; speedup vs baseline: 1.6240x; 1.6240x over previous
//
#include <hip/hip_runtime.h>
#include <hip/hip_bf16.h>

constexpr int BB = 4;
constexpr int TT = 1024;
constexpr int DD = 512;
constexpr int PP = 64;
constexpr int MM = 256;

// exp(2x) = exp2(CSCALE*x)
constexpr float CSCALE = 2.8853900817779268f; // 2*log2(e)

typedef __attribute__((ext_vector_type(8))) short v8s;
typedef __attribute__((ext_vector_type(4))) float v4f;

__device__ __forceinline__ unsigned short f2bf(float f) {
    unsigned u = __builtin_bit_cast(unsigned, f);
    unsigned r = (u + 0x7fffu + ((u >> 16) & 1u)) >> 16;
    return (unsigned short)r;
}

// Kernel 1: E1 = exp2(CSCALE*(x@W1+b1)); E2 = exp2(CSCALE*(x@W2+b2))
__global__ __launch_bounds__(256) void proj_kernel(
    const float* __restrict__ x, const float* __restrict__ W1, const float* __restrict__ b1,
    const float* __restrict__ W2, const float* __restrict__ b2,
    float* __restrict__ E1, float* __restrict__ E2) {
    int tid = threadIdx.x;
    int p = tid & 63;
    int rr = tid >> 6;
    int row0 = (blockIdx.x << 3) + (rr << 1);
    const float* xr0 = x + (size_t)row0 * DD;
    const float* xr1 = xr0 + DD;
    float a10 = b1[p], a11 = b1[p];
    float a20 = b2[p], a21 = b2[p];
    #pragma unroll 4
    for (int d = 0; d < DD; d++) {
        float wv1 = W1[d * PP + p];
        float wv2 = W2[d * PP + p];
        float x0 = xr0[d];
        float x1 = xr1[d];
        a10 = fmaf(x0, wv1, a10);
        a11 = fmaf(x1, wv1, a11);
        a20 = fmaf(x0, wv2, a20);
        a21 = fmaf(x1, wv2, a21);
    }
    E1[(size_t)row0 * PP + p]       = __builtin_amdgcn_exp2f(a10 * CSCALE);
    E1[(size_t)(row0 + 1) * PP + p] = __builtin_amdgcn_exp2f(a11 * CSCALE);
    E2[(size_t)row0 * PP + p]       = __builtin_amdgcn_exp2f(a20 * CSCALE);
    E2[(size_t)(row0 + 1) * PP + p] = __builtin_amdgcn_exp2f(a21 * CSCALE);
}

// Kernel 2: E3 = exp2(CSCALE*(ec@W3+b3))
__global__ __launch_bounds__(256) void ec_proj_kernel(
    const float* __restrict__ ec, const float* __restrict__ W3,
    const float* __restrict__ b3, float* __restrict__ E3) {
    int tid = threadIdx.x;
    int b = tid >> 6, p = tid & 63;
    float a = b3[p];
    const float* e = ec + (size_t)b * MM;
    #pragma unroll 4
    for (int m = 0; m < MM; m++) a = fmaf(e[m], W3[m * PP + p], a);
    E3[b * PP + p] = __builtin_amdgcn_exp2f(a * CSCALE);
}

// Kernel 3: transpose inputs -> Xt_bf16[b][d][u]
__global__ __launch_bounds__(256) void xt_kernel(
    const float* __restrict__ x, unsigned short* __restrict__ xt) {
    __shared__ float tile[64][65];
    int b = blockIdx.z;
    int d0 = blockIdx.x << 6;
    int u0 = blockIdx.y << 6;
    int tid = threadIdx.x;
    int c4 = (tid & 15) << 2, r = tid >> 4;
    #pragma unroll
    for (int i = 0; i < 4; i++) {
        int row = r + (i << 4);
        float4 v = *(const float4*)(x + ((size_t)b * TT + u0 + row) * DD + d0 + c4);
        tile[row][c4 + 0] = v.x;
        tile[row][c4 + 1] = v.y;
        tile[row][c4 + 2] = v.z;
        tile[row][c4 + 3] = v.w;
    }
    __syncthreads();
    int dd = tid >> 2;
    int uq = (tid & 3) << 4;
    unsigned short us[16];
    #pragma unroll
    for (int j = 0; j < 16; j++) us[j] = f2bf(tile[uq + j][dd]);
    uint4 w0, w1;
    w0.x = us[0] | ((unsigned)us[1] << 16);  w0.y = us[2] | ((unsigned)us[3] << 16);
    w0.z = us[4] | ((unsigned)us[5] << 16);  w0.w = us[6] | ((unsigned)us[7] << 16);
    w1.x = us[8] | ((unsigned)us[9] << 16);  w1.y = us[10] | ((unsigned)us[11] << 16);
    w1.z = us[12] | ((unsigned)us[13] << 16); w1.w = us[14] | ((unsigned)us[15] << 16);
    unsigned short* dst = xt + ((size_t)b * DD + d0 + dd) * TT + u0 + uq;
    *(uint4*)dst = w0;
    *(uint4*)(dst + 8) = w1;
}

// Kernel 4: scores + softmax, normalized at (fp32, in-place).
// Block = (b, 4 t's); lane: pp=tid&7 (8 p's), uu=tid>>3 (u within k-step).
__global__ __launch_bounds__(256) void scores_kernel(
    const float* __restrict__ E1, const float* __restrict__ E2,
    const float* __restrict__ E3, const float* __restrict__ wa_w,
    const float* __restrict__ wa_b, float* __restrict__ at) {
    __shared__ float sm[4][4];
    __shared__ float sl[4][4];
    int tid = threadIdx.x;
    int bid = blockIdx.x;
    int b = bid >> 8;
    int t0 = (bid & 255) << 2;
    int pp = tid & 7;
    int uu = tid >> 3;           // 0..31
    int p0 = pp << 3;

    // per-lane constants in registers
    float ww2[8], H[4][8];
    {
        float4 wv0 = *(const float4*)(wa_w + p0);
        float4 wv1 = *(const float4*)(wa_w + p0 + 4);
        ww2[0] = -2.f * wv0.x; ww2[1] = -2.f * wv0.y; ww2[2] = -2.f * wv0.z; ww2[3] = -2.f * wv0.w;
        ww2[4] = -2.f * wv1.x; ww2[5] = -2.f * wv1.y; ww2[6] = -2.f * wv1.z; ww2[7] = -2.f * wv1.w;
        float4 e3a = *(const float4*)(E3 + (b << 6) + p0);
        float4 e3b = *(const float4*)(E3 + (b << 6) + p0 + 4);
        #pragma unroll
        for (int i = 0; i < 4; i++) {
            const float* e1p = E1 + (((size_t)(b << 10) + t0 + i) << 6) + p0;
            float4 a = *(const float4*)e1p;
            float4 c = *(const float4*)(e1p + 4);
            H[i][0] = a.x * e3a.x; H[i][1] = a.y * e3a.y; H[i][2] = a.z * e3a.z; H[i][3] = a.w * e3a.w;
            H[i][4] = c.x * e3b.x; H[i][5] = c.y * e3b.y; H[i][6] = c.z * e3b.z; H[i][7] = c.w * e3b.w;
        }
    }
    // base = wa_b + sum_p wa_w
    float base;
    {
        float s = 0.f;
        #pragma unroll
        for (int j = 0; j < 8; j++) s += -0.5f * ww2[j];
        s += __shfl_xor(s, 1, 64);
        s += __shfl_xor(s, 2, 64);
        s += __shfl_xor(s, 4, 64);
        base = s + wa_b[0];
    }

    float m[4] = {-1e30f, -1e30f, -1e30f, -1e30f};
    float l[4] = {0.f, 0.f, 0.f, 0.f};

    for (int k = 0; k < 32; k++) {
        int u = (k << 5) + uu;
        const float* ep = E2 + (((size_t)(b << 10) + u) << 6) + p0;
        float4 e0 = *(const float4*)ep;
        float4 e1 = *(const float4*)(ep + 4);
        float ev[8] = {e0.x, e0.y, e0.z, e0.w, e1.x, e1.y, e1.z, e1.w};
        float s_sel = 0.f;
        #pragma unroll
        for (int i = 0; i < 4; i++) {
            float a0 = 0.f, a1 = 0.f;
            #pragma unroll
            for (int j = 0; j < 8; j += 2) {
                a0 = fmaf(ww2[j],   __builtin_amdgcn_rcpf(fmaf(H[i][j],   ev[j],   1.0f)), a0);
                a1 = fmaf(ww2[j+1], __builtin_amdgcn_rcpf(fmaf(H[i][j+1], ev[j+1], 1.0f)), a1);
            }
            float s = a0 + a1;
            s += __shfl_xor(s, 1, 64);
            s += __shfl_xor(s, 2, 64);
            s += __shfl_xor(s, 4, 64);
            s += base;
            float mn = fmaxf(m[i], s);
            l[i] = l[i] * __expf(m[i] - mn) + __expf(s - mn);
            m[i] = mn;
            s_sel = ((pp & 3) == i) ? s : s_sel;
        }
        if (pp < 4) {
            at[(((size_t)(b << 10) + t0 + pp) << 10) + u] = s_sel;
        }
    }
    // merge stats across uu lanes (pp lanes are redundant copies)
    #pragma unroll
    for (int i = 0; i < 4; i++) {
        #pragma unroll
        for (int off = 8; off <= 32; off <<= 1) {
            float m2 = __shfl_xor(m[i], off, 64);
            float l2 = __shfl_xor(l[i], off, 64);
            float mn = fmaxf(m[i], m2);
            l[i] = l[i] * __expf(m[i] - mn) + l2 * __expf(m2 - mn);
            m[i] = mn;
        }
    }
    int wv = tid >> 6;
    if ((tid & 63) == 0) {
        #pragma unroll
        for (int i = 0; i < 4; i++) { sm[wv][i] = m[i]; sl[wv][i] = l[i]; }
    }
    __syncthreads();   // also drains raw-score stores (vmcnt)
    float mx[4], inv[4];
    #pragma unroll
    for (int i = 0; i < 4; i++) {
        float mm = fmaxf(fmaxf(sm[0][i], sm[1][i]), fmaxf(sm[2][i], sm[3][i]));
        float L = sl[0][i] * __expf(sm[0][i] - mm) + sl[1][i] * __expf(sm[1][i] - mm)
                + sl[2][i] * __expf(sm[2][i] - mm) + sl[3][i] * __expf(sm[3][i] - mm);
        mx[i] = mm;
        inv[i] = 1.0f / L;
    }
    // phase 2: normalize in place
    #pragma unroll
    for (int i = 0; i < 4; i++) {
        size_t off = ((size_t)(b << 10) + t0 + i) << 10;
        float* prow = at + off + (tid << 2);
        float4 sv = *(const float4*)prow;
        sv.x = __expf(sv.x - mx[i]) * inv[i];
        sv.y = __expf(sv.y - mx[i]) * inv[i];
        sv.z = __expf(sv.z - mx[i]) * inv[i];
        sv.w = __expf(sv.w - mx[i]) * inv[i];
        *(float4*)prow = sv;
    }
}

// Kernel 5: out[b] = at[b] @ X[b] via bf16 MFMA. A = at fp32 (cvt at staging),
// B = Xt_bf16 [n][k] (k-contiguous). 64x64 tile, BK=64, 4 waves of 32x32.
__global__ __launch_bounds__(256) void av_mfma_kernel(
    const float* __restrict__ at, const unsigned short* __restrict__ xt,
    float* __restrict__ out) {
    __shared__ unsigned short As[64][80];  // [m][k] +16 pad
    __shared__ unsigned short Bs[64][80];  // [n][k]
    int b = blockIdx.z;
    int m0 = blockIdx.y << 6;
    int n0 = blockIdx.x << 6;
    const float* A = at + ((size_t)b << 20);
    const unsigned short* Bt = xt + ((size_t)b * DD) * TT;
    int tid = threadIdx.x;
    int lane = tid & 63;
    int wv = tid >> 6;
    int wm = (wv & 1) << 5;
    int wn = (wv >> 1) << 5;
    int l15 = lane & 15;
    int quad = lane >> 4;

    v4f acc00 = {0.f, 0.f, 0.f, 0.f}, acc01 = acc00, acc10 = acc00, acc11 = acc00;

    for (int k0 = 0; k0 < TT; k0 += 64) {
        __syncthreads();
        // stage A: 64x64 fp32 -> bf16. 1024 float4-slots, 4 per thread.
        #pragma unroll
        for (int i = 0; i < 4; i++) {
            int s = (i << 8) + tid;
            int row = s >> 4, k4 = (s & 15) << 2;
            float4 v = *(const float4*)(A + (size_t)(m0 + row) * TT + k0 + k4);
            unsigned short* d = &As[row][k4];
            d[0] = f2bf(v.x); d[1] = f2bf(v.y); d[2] = f2bf(v.z); d[3] = f2bf(v.w);
        }
        // stage B: 64x64 bf16, 512 ushort8-slots, 2 per thread.
        #pragma unroll
        for (int i = 0; i < 2; i++) {
            int s = (i << 8) + tid;
            int row = s >> 3, k8 = (s & 7) << 3;
            uint4 v = *(const uint4*)(Bt + (size_t)(n0 + row) * TT + k0 + k8);
            *(uint4*)&Bs[row][k8] = v;
        }
        __syncthreads();
        #pragma unroll
        for (int kq = 0; kq < 2; kq++) {
            int kc = (kq << 5) + (quad << 3);
            v8s a0 = *(const v8s*)&As[wm + l15][kc];
            v8s a1 = *(const v8s*)&As[wm + 16 + l15][kc];
            v8s b0 = *(const v8s*)&Bs[wn + l15][kc];
            v8s b1 = *(const v8s*)&Bs[wn + 16 + l15][kc];
            acc00 = __builtin_amdgcn_mfma_f32_16x16x32_bf16(a0, b0, acc00, 0, 0, 0);
            acc01 = __builtin_amdgcn_mfma_f32_16x16x32_bf16(a0, b1, acc01, 0, 0, 0);
            acc10 = __builtin_amdgcn_mfma_f32_16x16x32_bf16(a1, b0, acc10, 0, 0, 0);
            acc11 = __builtin_amdgcn_mfma_f32_16x16x32_bf16(a1, b1, acc11, 0, 0, 0);
        }
    }
    // epilogue: C/D layout col=lane&15, row=quad*4+reg
    float* C = out + ((size_t)b * TT) * DD;
    int rbase = m0 + wm + (quad << 2);
    int cn = n0 + wn + l15;
    #pragma unroll
    for (int r = 0; r < 4; r++) {
        C[(size_t)(rbase + r) * DD + cn]           = acc00[r];
        C[(size_t)(rbase + r) * DD + cn + 16]      = acc01[r];
        C[(size_t)(rbase + 16 + r) * DD + cn]      = acc10[r];
        C[(size_t)(rbase + 16 + r) * DD + cn + 16] = acc11[r];
    }
}

extern "C" void kernel_launch(void* const* d_in, const int* in_sizes, int n_in,
                              void* d_out, int out_size, void* d_ws, size_t ws_size,
                              hipStream_t stream) {
    const float* inputs = (const float*)d_in[0];
    const float* ec     = (const float*)d_in[1];
    const float* W1     = (const float*)d_in[2];
    const float* b1     = (const float*)d_in[3];
    const float* W2     = (const float*)d_in[4];
    const float* b2     = (const float*)d_in[5];
    const float* W3     = (const float*)d_in[6];
    const float* b3     = (const float*)d_in[7];
    const float* wa_w   = (const float*)d_in[8];
    const float* wa_b   = (const float*)d_in[9];
    float* out = (float*)d_out;

    // ws (floats): E1[262144] | E2[262144] | E3[512] | at[4194304] | xt[1048576 f-slots = 2M bf16]
    float* ws = (float*)d_ws;
    float* E1 = ws;
    float* E2 = ws + 262144;
    float* E3 = ws + 524288;
    float* at = ws + 524800;
    unsigned short* xt = (unsigned short*)(ws + 4719104);
    // total 23.1 MB

    hipLaunchKernelGGL(proj_kernel, dim3(512), dim3(256), 0, stream,
                       inputs, W1, b1, W2, b2, E1, E2);
    hipLaunchKernelGGL(ec_proj_kernel, dim3(1), dim3(256), 0, stream,
                       ec, W3, b3, E3);
    hipLaunchKernelGGL(xt_kernel, dim3(8, 16, 4), dim3(256), 0, stream,
                       inputs, xt);
    hipLaunchKernelGGL(scores_kernel, dim3(1024), dim3(256), 0, stream,
                       E1, E2, E3, wa_w, wa_b, at);
    hipLaunchKernelGGL(av_mfma_kernel, dim3(8, 16, 4), dim3(256), 0, stream,
                       at, xt, out);
}

// Round 4
// 174.511 us; speedup vs baseline: 2.1427x; 1.3194x over previous
//
#include <hip/hip_runtime.h>
#include <hip/hip_bf16.h>

constexpr int BB = 4;
constexpr int TT = 1024;
constexpr int DD = 512;
constexpr int PP = 64;
constexpr int MM = 256;

// exp(2x) = exp2(CSCALE*x)
constexpr float CSCALE = 2.8853900817779268f; // 2*log2(e)
constexpr float L2E = 1.4426950408889634f;    // log2(e)

typedef __attribute__((ext_vector_type(8))) short v8s;
typedef __attribute__((ext_vector_type(4))) float v4f;

__device__ __forceinline__ unsigned short f2bf(float f) {
    unsigned u = __builtin_bit_cast(unsigned, f);
    unsigned r = (u + 0x7fffu + ((u >> 16) & 1u)) >> 16;
    return (unsigned short)r;
}

// Merged prep: blocks [0,512) proj, [512,1024) xt transpose, 1024 ec_proj.
__global__ __launch_bounds__(256) void prep_kernel(
    const float* __restrict__ x, const float* __restrict__ ec,
    const float* __restrict__ W1, const float* __restrict__ b1,
    const float* __restrict__ W2, const float* __restrict__ b2,
    const float* __restrict__ W3, const float* __restrict__ b3,
    float* __restrict__ E1, float* __restrict__ E2, float* __restrict__ E3,
    unsigned short* __restrict__ xt) {
    __shared__ float tile[64][65];
    int bid = blockIdx.x;
    int tid = threadIdx.x;
    if (bid < 512) {
        // proj: E1 = exp2(CSCALE*(x@W1+b1)); E2 likewise
        int p = tid & 63;
        int rr = tid >> 6;
        int row0 = (bid << 3) + (rr << 1);
        const float* xr0 = x + (size_t)row0 * DD;
        const float* xr1 = xr0 + DD;
        float a10 = b1[p], a11 = b1[p];
        float a20 = b2[p], a21 = b2[p];
        #pragma unroll 4
        for (int d = 0; d < DD; d++) {
            float wv1 = W1[d * PP + p];
            float wv2 = W2[d * PP + p];
            float x0 = xr0[d];
            float x1 = xr1[d];
            a10 = fmaf(x0, wv1, a10);
            a11 = fmaf(x1, wv1, a11);
            a20 = fmaf(x0, wv2, a20);
            a21 = fmaf(x1, wv2, a21);
        }
        E1[(size_t)row0 * PP + p]       = __builtin_amdgcn_exp2f(a10 * CSCALE);
        E1[(size_t)(row0 + 1) * PP + p] = __builtin_amdgcn_exp2f(a11 * CSCALE);
        E2[(size_t)row0 * PP + p]       = __builtin_amdgcn_exp2f(a20 * CSCALE);
        E2[(size_t)(row0 + 1) * PP + p] = __builtin_amdgcn_exp2f(a21 * CSCALE);
    } else if (bid < 1024) {
        // xt: transpose inputs -> bf16 [b][d][u]
        int q = bid - 512;
        int d0 = (q & 7) << 6;
        int u0 = ((q >> 3) & 15) << 6;
        int b = q >> 7;
        int c4 = (tid & 15) << 2, r = tid >> 4;
        #pragma unroll
        for (int i = 0; i < 4; i++) {
            int row = r + (i << 4);
            float4 v = *(const float4*)(x + ((size_t)b * TT + u0 + row) * DD + d0 + c4);
            tile[row][c4 + 0] = v.x;
            tile[row][c4 + 1] = v.y;
            tile[row][c4 + 2] = v.z;
            tile[row][c4 + 3] = v.w;
        }
        __syncthreads();
        int dd = tid >> 2;
        int uq = (tid & 3) << 4;
        unsigned short us[16];
        #pragma unroll
        for (int j = 0; j < 16; j++) us[j] = f2bf(tile[uq + j][dd]);
        uint4 w0, w1;
        w0.x = us[0] | ((unsigned)us[1] << 16);  w0.y = us[2] | ((unsigned)us[3] << 16);
        w0.z = us[4] | ((unsigned)us[5] << 16);  w0.w = us[6] | ((unsigned)us[7] << 16);
        w1.x = us[8] | ((unsigned)us[9] << 16);  w1.y = us[10] | ((unsigned)us[11] << 16);
        w1.z = us[12] | ((unsigned)us[13] << 16); w1.w = us[14] | ((unsigned)us[15] << 16);
        unsigned short* dst = xt + ((size_t)b * DD + d0 + dd) * TT + u0 + uq;
        *(uint4*)dst = w0;
        *(uint4*)(dst + 8) = w1;
    } else {
        // ec_proj: E3 = exp2(CSCALE*(ec@W3+b3))
        int b = tid >> 6, p = tid & 63;
        float a = b3[p];
        const float* e = ec + (size_t)b * MM;
        #pragma unroll 4
        for (int m = 0; m < MM; m++) a = fmaf(e[m], W3[m * PP + p], a);
        E3[b * PP + p] = __builtin_amdgcn_exp2f(a * CSCALE);
    }
}

// scores: block = (b, 4 t rows). lane: pp=tid&7 (8 p's), uu=tid>>3 (u slot).
// Raw scores (pre-scaled by log2 e) go to LDS [k][tid]; deferred softmax;
// normalized at written directly as bf16.
__global__ __launch_bounds__(256) void scores_kernel(
    const float* __restrict__ E1, const float* __restrict__ E2,
    const float* __restrict__ E3, const float* __restrict__ wa_w,
    const float* __restrict__ wa_b, unsigned short* __restrict__ at_bf) {
    __shared__ float sc_lds[32][256];   // 32 KB
    __shared__ float sm[4][4];
    __shared__ float sl[4][4];
    int tid = threadIdx.x;
    int bid = blockIdx.x;
    int b = bid >> 8;
    int t0 = (bid & 255) << 2;
    int pp = tid & 7;
    int uu = tid >> 3;           // 0..31
    int p0 = pp << 3;
    int lane = tid & 63;
    int wv = tid >> 6;
    int my_i = pp & 3;

    float ww2[8], H[4][8];
    float base;
    {
        float4 wv0 = *(const float4*)(wa_w + p0);
        float4 wv1 = *(const float4*)(wa_w + p0 + 4);
        float s = wv0.x + wv0.y + wv0.z + wv0.w + wv1.x + wv1.y + wv1.z + wv1.w;
        s += __shfl_xor(s, 1, 64);
        s += __shfl_xor(s, 2, 64);
        s += __shfl_xor(s, 4, 64);
        base = (s + wa_b[0]) * L2E;
        ww2[0] = -2.f * L2E * wv0.x; ww2[1] = -2.f * L2E * wv0.y;
        ww2[2] = -2.f * L2E * wv0.z; ww2[3] = -2.f * L2E * wv0.w;
        ww2[4] = -2.f * L2E * wv1.x; ww2[5] = -2.f * L2E * wv1.y;
        ww2[6] = -2.f * L2E * wv1.z; ww2[7] = -2.f * L2E * wv1.w;
        float4 e3a = *(const float4*)(E3 + (b << 6) + p0);
        float4 e3b = *(const float4*)(E3 + (b << 6) + p0 + 4);
        #pragma unroll
        for (int i = 0; i < 4; i++) {
            const float* e1p = E1 + (((size_t)(b << 10) + t0 + i) << 6) + p0;
            float4 a = *(const float4*)e1p;
            float4 c = *(const float4*)(e1p + 4);
            H[i][0] = a.x * e3a.x; H[i][1] = a.y * e3a.y; H[i][2] = a.z * e3a.z; H[i][3] = a.w * e3a.w;
            H[i][4] = c.x * e3b.x; H[i][5] = c.y * e3b.y; H[i][6] = c.z * e3b.z; H[i][7] = c.w * e3b.w;
        }
    }

    float mown = -1e30f;
    for (int k = 0; k < 32; k++) {
        int u = (k << 5) + uu;
        const float* ep = E2 + (((size_t)(b << 10) + u) << 6) + p0;
        float4 e0 = *(const float4*)ep;
        float4 e1 = *(const float4*)(ep + 4);
        float ev[8] = {e0.x, e0.y, e0.z, e0.w, e1.x, e1.y, e1.z, e1.w};
        float own = 0.f;
        #pragma unroll
        for (int i = 0; i < 4; i++) {
            float a0 = 0.f, a1 = 0.f;
            #pragma unroll
            for (int j = 0; j < 8; j += 2) {
                a0 = fmaf(ww2[j],   __builtin_amdgcn_rcpf(fmaf(H[i][j],   ev[j],   1.0f)), a0);
                a1 = fmaf(ww2[j+1], __builtin_amdgcn_rcpf(fmaf(H[i][j+1], ev[j+1], 1.0f)), a1);
            }
            float s = a0 + a1;
            s += __shfl_xor(s, 1, 64);
            s += __shfl_xor(s, 2, 64);
            s += __shfl_xor(s, 4, 64);
            own = (my_i == i) ? s : own;
        }
        own += base;
        sc_lds[k][tid] = own;
        mown = fmaxf(mown, own);
    }
    // wave max for own i (xor4 = pp twin, xor8/16/32 = uu)
    mown = fmaxf(mown, __shfl_xor(mown, 4, 64));
    mown = fmaxf(mown, __shfl_xor(mown, 8, 64));
    mown = fmaxf(mown, __shfl_xor(mown, 16, 64));
    mown = fmaxf(mown, __shfl_xor(mown, 32, 64));
    if (lane < 4) sm[wv][lane] = mown;
    __syncthreads();
    float mx = fmaxf(fmaxf(sm[0][my_i], sm[1][my_i]), fmaxf(sm[2][my_i], sm[3][my_i]));

    float l = 0.f;
    for (int k = 0; k < 32; k++) {
        float s = sc_lds[k][tid];
        float e = __builtin_amdgcn_exp2f(s - mx);
        sc_lds[k][tid] = e;
        l += e;
    }
    l += __shfl_xor(l, 8, 64);
    l += __shfl_xor(l, 16, 64);
    l += __shfl_xor(l, 32, 64);
    if (lane < 4) sl[wv][lane] = l;
    __syncthreads();
    float inv = 1.0f / (sl[0][my_i] + sl[1][my_i] + sl[2][my_i] + sl[3][my_i]);

    if (pp < 4) {
        size_t rowbase = ((size_t)((b << 10) + t0 + my_i)) << 10;
        for (int k = 0; k < 32; k++) {
            float e = sc_lds[k][tid] * inv;
            at_bf[rowbase + (k << 5) + uu] = f2bf(e);
        }
    }
}

// av: out[b] = at_bf[b] (1024x1024 bf16) @ Xt[b]^T via MFMA.
// 64x64 tile, BK=64, 4 waves each 32x32 (2x2 of 16x16x32).
__global__ __launch_bounds__(256) void av_mfma_kernel(
    const unsigned short* __restrict__ at_bf, const unsigned short* __restrict__ xt,
    float* __restrict__ out) {
    __shared__ unsigned short As[64][72];  // [m][k], +8 pad -> 2-way (free) banks
    __shared__ unsigned short Bs[64][72];  // [n][k]
    int b = blockIdx.z;
    int m0 = blockIdx.y << 6;
    int n0 = blockIdx.x << 6;
    const unsigned short* A = at_bf + ((size_t)b << 20);
    const unsigned short* Bt = xt + (size_t)b * DD * TT;
    int tid = threadIdx.x;
    int lane = tid & 63;
    int wv = tid >> 6;
    int wm = (wv & 1) << 5;
    int wn = (wv >> 1) << 5;
    int l15 = lane & 15;
    int quad = lane >> 4;

    v4f acc00 = {0.f, 0.f, 0.f, 0.f}, acc01 = acc00, acc10 = acc00, acc11 = acc00;

    for (int k0 = 0; k0 < TT; k0 += 64) {
        __syncthreads();
        // stage A+B: 512 uint4-slots each, 2 per thread
        #pragma unroll
        for (int i = 0; i < 2; i++) {
            int s = (i << 8) + tid;
            int row = s >> 3, k8 = (s & 7) << 3;
            uint4 va = *(const uint4*)(A + (size_t)(m0 + row) * TT + k0 + k8);
            *(uint4*)&As[row][k8] = va;
            uint4 vb = *(const uint4*)(Bt + (size_t)(n0 + row) * TT + k0 + k8);
            *(uint4*)&Bs[row][k8] = vb;
        }
        __syncthreads();
        #pragma unroll
        for (int kq = 0; kq < 2; kq++) {
            int kc = (kq << 5) + (quad << 3);
            v8s a0 = *(const v8s*)&As[wm + l15][kc];
            v8s a1 = *(const v8s*)&As[wm + 16 + l15][kc];
            v8s b0 = *(const v8s*)&Bs[wn + l15][kc];
            v8s b1 = *(const v8s*)&Bs[wn + 16 + l15][kc];
            acc00 = __builtin_amdgcn_mfma_f32_16x16x32_bf16(a0, b0, acc00, 0, 0, 0);
            acc01 = __builtin_amdgcn_mfma_f32_16x16x32_bf16(a0, b1, acc01, 0, 0, 0);
            acc10 = __builtin_amdgcn_mfma_f32_16x16x32_bf16(a1, b0, acc10, 0, 0, 0);
            acc11 = __builtin_amdgcn_mfma_f32_16x16x32_bf16(a1, b1, acc11, 0, 0, 0);
        }
    }
    // C/D layout: col = lane&15, row = quad*4 + reg
    float* C = out + (size_t)b * TT * DD;
    int rbase = m0 + wm + (quad << 2);
    int cn = n0 + wn + l15;
    #pragma unroll
    for (int r = 0; r < 4; r++) {
        C[(size_t)(rbase + r) * DD + cn]           = acc00[r];
        C[(size_t)(rbase + r) * DD + cn + 16]      = acc01[r];
        C[(size_t)(rbase + 16 + r) * DD + cn]      = acc10[r];
        C[(size_t)(rbase + 16 + r) * DD + cn + 16] = acc11[r];
    }
}

extern "C" void kernel_launch(void* const* d_in, const int* in_sizes, int n_in,
                              void* d_out, int out_size, void* d_ws, size_t ws_size,
                              hipStream_t stream) {
    const float* inputs = (const float*)d_in[0];
    const float* ec     = (const float*)d_in[1];
    const float* W1     = (const float*)d_in[2];
    const float* b1     = (const float*)d_in[3];
    const float* W2     = (const float*)d_in[4];
    const float* b2     = (const float*)d_in[5];
    const float* W3     = (const float*)d_in[6];
    const float* b3     = (const float*)d_in[7];
    const float* wa_w   = (const float*)d_in[8];
    const float* wa_b   = (const float*)d_in[9];
    float* out = (float*)d_out;

    // ws (float units): E1[262144] | E2[262144] | E3[512] | at_bf (2097152 f-slots = 4.2M bf16)
    //                  | xt (1048576 f-slots = 2.1M bf16).  Total ~14.7 MB.
    float* ws = (float*)d_ws;
    float* E1 = ws;
    float* E2 = ws + 262144;
    float* E3 = ws + 524288;
    unsigned short* at_bf = (unsigned short*)(ws + 524800);
    unsigned short* xt    = (unsigned short*)(ws + 524800 + 2097152);

    hipLaunchKernelGGL(prep_kernel, dim3(1025), dim3(256), 0, stream,
                       inputs, ec, W1, b1, W2, b2, W3, b3, E1, E2, E3, xt);
    hipLaunchKernelGGL(scores_kernel, dim3(1024), dim3(256), 0, stream,
                       E1, E2, E3, wa_w, wa_b, at_bf);
    hipLaunchKernelGGL(av_mfma_kernel, dim3(DD / 64, TT / 64, BB), dim3(256), 0, stream,
                       at_bf, xt, out);
}

// Round 5
// 173.317 us; speedup vs baseline: 2.1574x; 1.0069x over previous
//
#include <hip/hip_runtime.h>
#include <hip/hip_bf16.h>

constexpr int BB = 4;
constexpr int TT = 1024;
constexpr int DD = 512;
constexpr int PP = 64;
constexpr int MM = 256;

// exp(2x) = exp2(CSCALE*x)
constexpr float CSCALE = 2.8853900817779268f; // 2*log2(e)
constexpr float L2E = 1.4426950408889634f;    // log2(e)

typedef __attribute__((ext_vector_type(8))) short v8s;
typedef __attribute__((ext_vector_type(4))) float v4f;

__device__ __forceinline__ unsigned short f2bf(float f) {
    unsigned u = __builtin_bit_cast(unsigned, f);
    unsigned r = (u + 0x7fffu + ((u >> 16) & 1u)) >> 16;
    return (unsigned short)r;
}
__device__ __forceinline__ float bf2f(unsigned short h) {
    return __builtin_bit_cast(float, (unsigned)h << 16);
}
__device__ __forceinline__ void split2(float v, unsigned short& h, unsigned short& l) {
    unsigned short hh = f2bf(v);
    h = hh;
    l = f2bf(v - bf2f(hh));
}

// prep: blocks [0,64): proj GEMM (bf16-split MFMA); [64,576): xt transpose; 576: ec_proj.
// proj: h = x (4096x512) @ [W1|W2] (512x128); E1/E2 = exp2(CSCALE*(h+bias)).
__global__ __launch_bounds__(256) void prep_kernel(
    const float* __restrict__ x, const float* __restrict__ ec,
    const float* __restrict__ W1, const float* __restrict__ b1,
    const float* __restrict__ W2, const float* __restrict__ b2,
    const float* __restrict__ W3, const float* __restrict__ b3,
    float* __restrict__ E1, float* __restrict__ E2, float* __restrict__ E3,
    unsigned short* __restrict__ xt) {
    __shared__ unsigned short AsH[64][72];   // [m][k] bf16-hi of x tile
    __shared__ unsigned short AsL[64][72];   // bf16-lo
    __shared__ unsigned short BsH[128][72];  // [n][k] bf16-hi of [W1|W2]^T tile
    __shared__ unsigned short BsL[128][72];  // total 55.3 KB
    int bid = blockIdx.x;
    int tid = threadIdx.x;

    if (bid < 64) {
        int m0 = bid << 6;
        int lane = tid & 63;
        int wv = tid >> 6;
        int wm = (wv & 1) << 5;        // 0/32
        int wn = (wv >> 1) << 6;       // 0/64
        int l15 = lane & 15;
        int quad = lane >> 4;

        v4f acc[2][4];
        #pragma unroll
        for (int mt = 0; mt < 2; mt++)
            #pragma unroll
            for (int nt = 0; nt < 4; nt++) acc[mt][nt] = (v4f){0.f, 0.f, 0.f, 0.f};

        for (int k0 = 0; k0 < DD; k0 += 64) {
            __syncthreads();
            // stage A: 64 rows x 64 k fp32 -> hi/lo bf16. 1024 float4 slots, 4/thread.
            #pragma unroll
            for (int i = 0; i < 4; i++) {
                int s = (i << 8) + tid;
                int row = s >> 4, k4 = (s & 15) << 2;
                float4 v = *(const float4*)(x + (size_t)(m0 + row) * DD + k0 + k4);
                unsigned short h0, h1, h2, h3, l0, l1, l2, l3;
                split2(v.x, h0, l0); split2(v.y, h1, l1);
                split2(v.z, h2, l2); split2(v.w, h3, l3);
                uint2 hw, lw;
                hw.x = h0 | ((unsigned)h1 << 16); hw.y = h2 | ((unsigned)h3 << 16);
                lw.x = l0 | ((unsigned)l1 << 16); lw.y = l2 | ((unsigned)l3 << 16);
                *(uint2*)&AsH[row][k4] = hw;
                *(uint2*)&AsL[row][k4] = lw;
            }
            // stage B: 64 k x 128 n fp32 -> transposed hi/lo. 2048 float4 slots, 8/thread.
            #pragma unroll
            for (int i = 0; i < 8; i++) {
                int s = (i << 8) + tid;
                int kk = s >> 5, n4 = (s & 31) << 2;
                const float* src = (n4 < 64) ? (W1 + (size_t)(k0 + kk) * PP + n4)
                                             : (W2 + (size_t)(k0 + kk) * PP + (n4 - 64));
                float4 v = *(const float4*)src;
                unsigned short h, l;
                split2(v.x, h, l); BsH[n4 + 0][kk] = h; BsL[n4 + 0][kk] = l;
                split2(v.y, h, l); BsH[n4 + 1][kk] = h; BsL[n4 + 1][kk] = l;
                split2(v.z, h, l); BsH[n4 + 2][kk] = h; BsL[n4 + 2][kk] = l;
                split2(v.w, h, l); BsH[n4 + 3][kk] = h; BsL[n4 + 3][kk] = l;
            }
            __syncthreads();
            #pragma unroll
            for (int kk = 0; kk < 64; kk += 32) {
                int kc = kk + (quad << 3);
                v8s aH[2], aL[2], bH[4], bL[4];
                #pragma unroll
                for (int mt = 0; mt < 2; mt++) {
                    aH[mt] = *(const v8s*)&AsH[wm + (mt << 4) + l15][kc];
                    aL[mt] = *(const v8s*)&AsL[wm + (mt << 4) + l15][kc];
                }
                #pragma unroll
                for (int nt = 0; nt < 4; nt++) {
                    bH[nt] = *(const v8s*)&BsH[wn + (nt << 4) + l15][kc];
                    bL[nt] = *(const v8s*)&BsL[wn + (nt << 4) + l15][kc];
                }
                #pragma unroll
                for (int mt = 0; mt < 2; mt++)
                    #pragma unroll
                    for (int nt = 0; nt < 4; nt++) {
                        acc[mt][nt] = __builtin_amdgcn_mfma_f32_16x16x32_bf16(aH[mt], bH[nt], acc[mt][nt], 0, 0, 0);
                        acc[mt][nt] = __builtin_amdgcn_mfma_f32_16x16x32_bf16(aH[mt], bL[nt], acc[mt][nt], 0, 0, 0);
                        acc[mt][nt] = __builtin_amdgcn_mfma_f32_16x16x32_bf16(aL[mt], bH[nt], acc[mt][nt], 0, 0, 0);
                    }
            }
        }
        // epilogue: row = m0+wm+mt*16+quad*4+r, col n = wn+nt*16+l15
        #pragma unroll
        for (int nt = 0; nt < 4; nt++) {
            int n = wn + (nt << 4) + l15;
            int p = n & 63;
            float bias = (n < 64) ? b1[p] : b2[p];
            float* E = (n < 64) ? E1 : E2;
            #pragma unroll
            for (int mt = 0; mt < 2; mt++) {
                int rbase = m0 + wm + (mt << 4) + (quad << 2);
                #pragma unroll
                for (int r = 0; r < 4; r++) {
                    float h = acc[mt][nt][r] + bias;
                    E[(size_t)(rbase + r) * PP + p] = __builtin_amdgcn_exp2f(h * CSCALE);
                }
            }
        }
    } else if (bid < 576) {
        // xt: transpose inputs -> bf16 [b][d][u]; reuse AsH.. as raw LDS
        float (*tile)[65] = (float(*)[65])&AsH[0][0];   // 64x65 floats = 16.6KB < 55KB
        int q = bid - 64;
        int d0 = (q & 7) << 6;
        int u0 = ((q >> 3) & 15) << 6;
        int b = q >> 7;
        int c4 = (tid & 15) << 2, r = tid >> 4;
        #pragma unroll
        for (int i = 0; i < 4; i++) {
            int row = r + (i << 4);
            float4 v = *(const float4*)(x + ((size_t)b * TT + u0 + row) * DD + d0 + c4);
            tile[row][c4 + 0] = v.x;
            tile[row][c4 + 1] = v.y;
            tile[row][c4 + 2] = v.z;
            tile[row][c4 + 3] = v.w;
        }
        __syncthreads();
        int dd = tid >> 2;
        int uq = (tid & 3) << 4;
        unsigned short us[16];
        #pragma unroll
        for (int j = 0; j < 16; j++) us[j] = f2bf(tile[uq + j][dd]);
        uint4 w0, w1;
        w0.x = us[0] | ((unsigned)us[1] << 16);  w0.y = us[2] | ((unsigned)us[3] << 16);
        w0.z = us[4] | ((unsigned)us[5] << 16);  w0.w = us[6] | ((unsigned)us[7] << 16);
        w1.x = us[8] | ((unsigned)us[9] << 16);  w1.y = us[10] | ((unsigned)us[11] << 16);
        w1.z = us[12] | ((unsigned)us[13] << 16); w1.w = us[14] | ((unsigned)us[15] << 16);
        unsigned short* dst = xt + ((size_t)b * DD + d0 + dd) * TT + u0 + uq;
        *(uint4*)dst = w0;
        *(uint4*)(dst + 8) = w1;
    } else {
        // ec_proj: E3 = exp2(CSCALE*(ec@W3+b3))
        int b = tid >> 6, p = tid & 63;
        float a = b3[p];
        const float* e = ec + (size_t)b * MM;
        #pragma unroll 4
        for (int m = 0; m < MM; m++) a = fmaf(e[m], W3[m * PP + p], a);
        E3[b * PP + p] = __builtin_amdgcn_exp2f(a * CSCALE);
    }
}

// scores: block = (b, 4 t rows). lane: pp=tid&7 (8 p's), uu=tid>>3 (u slot).
__global__ __launch_bounds__(256) void scores_kernel(
    const float* __restrict__ E1, const float* __restrict__ E2,
    const float* __restrict__ E3, const float* __restrict__ wa_w,
    const float* __restrict__ wa_b, unsigned short* __restrict__ at_bf) {
    __shared__ float sc_lds[32][256];   // 32 KB
    __shared__ float sm[4][4];
    __shared__ float sl[4][4];
    int tid = threadIdx.x;
    int bid = blockIdx.x;
    int b = bid >> 8;
    int t0 = (bid & 255) << 2;
    int pp = tid & 7;
    int uu = tid >> 3;           // 0..31
    int p0 = pp << 3;
    int lane = tid & 63;
    int wv = tid >> 6;
    int my_i = pp & 3;

    float ww2[8], H[4][8];
    float base;
    {
        float4 wv0 = *(const float4*)(wa_w + p0);
        float4 wv1 = *(const float4*)(wa_w + p0 + 4);
        float s = wv0.x + wv0.y + wv0.z + wv0.w + wv1.x + wv1.y + wv1.z + wv1.w;
        s += __shfl_xor(s, 1, 64);
        s += __shfl_xor(s, 2, 64);
        s += __shfl_xor(s, 4, 64);
        base = (s + wa_b[0]) * L2E;
        ww2[0] = -2.f * L2E * wv0.x; ww2[1] = -2.f * L2E * wv0.y;
        ww2[2] = -2.f * L2E * wv0.z; ww2[3] = -2.f * L2E * wv0.w;
        ww2[4] = -2.f * L2E * wv1.x; ww2[5] = -2.f * L2E * wv1.y;
        ww2[6] = -2.f * L2E * wv1.z; ww2[7] = -2.f * L2E * wv1.w;
        float4 e3a = *(const float4*)(E3 + (b << 6) + p0);
        float4 e3b = *(const float4*)(E3 + (b << 6) + p0 + 4);
        #pragma unroll
        for (int i = 0; i < 4; i++) {
            const float* e1p = E1 + (((size_t)(b << 10) + t0 + i) << 6) + p0;
            float4 a = *(const float4*)e1p;
            float4 c = *(const float4*)(e1p + 4);
            H[i][0] = a.x * e3a.x; H[i][1] = a.y * e3a.y; H[i][2] = a.z * e3a.z; H[i][3] = a.w * e3a.w;
            H[i][4] = c.x * e3b.x; H[i][5] = c.y * e3b.y; H[i][6] = c.z * e3b.z; H[i][7] = c.w * e3b.w;
        }
    }

    float mown = -1e30f;
    for (int k = 0; k < 32; k++) {
        int u = (k << 5) + uu;
        const float* ep = E2 + (((size_t)(b << 10) + u) << 6) + p0;
        float4 e0 = *(const float4*)ep;
        float4 e1 = *(const float4*)(ep + 4);
        float ev[8] = {e0.x, e0.y, e0.z, e0.w, e1.x, e1.y, e1.z, e1.w};
        float own = 0.f;
        #pragma unroll
        for (int i = 0; i < 4; i++) {
            float a0 = 0.f, a1 = 0.f;
            #pragma unroll
            for (int j = 0; j < 8; j += 2) {
                a0 = fmaf(ww2[j],   __builtin_amdgcn_rcpf(fmaf(H[i][j],   ev[j],   1.0f)), a0);
                a1 = fmaf(ww2[j+1], __builtin_amdgcn_rcpf(fmaf(H[i][j+1], ev[j+1], 1.0f)), a1);
            }
            float s = a0 + a1;
            s += __shfl_xor(s, 1, 64);
            s += __shfl_xor(s, 2, 64);
            s += __shfl_xor(s, 4, 64);
            own = (my_i == i) ? s : own;
        }
        own += base;
        sc_lds[k][tid] = own;
        mown = fmaxf(mown, own);
    }
    mown = fmaxf(mown, __shfl_xor(mown, 4, 64));
    mown = fmaxf(mown, __shfl_xor(mown, 8, 64));
    mown = fmaxf(mown, __shfl_xor(mown, 16, 64));
    mown = fmaxf(mown, __shfl_xor(mown, 32, 64));
    if (lane < 4) sm[wv][lane] = mown;
    __syncthreads();
    float mx = fmaxf(fmaxf(sm[0][my_i], sm[1][my_i]), fmaxf(sm[2][my_i], sm[3][my_i]));

    float l = 0.f;
    for (int k = 0; k < 32; k++) {
        float s = sc_lds[k][tid];
        float e = __builtin_amdgcn_exp2f(s - mx);
        sc_lds[k][tid] = e;
        l += e;
    }
    l += __shfl_xor(l, 8, 64);
    l += __shfl_xor(l, 16, 64);
    l += __shfl_xor(l, 32, 64);
    if (lane < 4) sl[wv][lane] = l;
    __syncthreads();
    float inv = 1.0f / (sl[0][my_i] + sl[1][my_i] + sl[2][my_i] + sl[3][my_i]);

    if (pp < 4) {
        size_t rowbase = ((size_t)((b << 10) + t0 + my_i)) << 10;
        for (int k = 0; k < 32; k++) {
            float e = sc_lds[k][tid] * inv;
            at_bf[rowbase + (k << 5) + uu] = f2bf(e);
        }
    }
}

// av: out[b] = at_bf[b] (1024x1024 bf16) @ Xt[b]^T via MFMA. 64x64 tile, BK=64.
__global__ __launch_bounds__(256) void av_mfma_kernel(
    const unsigned short* __restrict__ at_bf, const unsigned short* __restrict__ xt,
    float* __restrict__ out) {
    __shared__ unsigned short As[64][72];
    __shared__ unsigned short Bs[64][72];
    int b = blockIdx.z;
    int m0 = blockIdx.y << 6;
    int n0 = blockIdx.x << 6;
    const unsigned short* A = at_bf + ((size_t)b << 20);
    const unsigned short* Bt = xt + (size_t)b * DD * TT;
    int tid = threadIdx.x;
    int lane = tid & 63;
    int wv = tid >> 6;
    int wm = (wv & 1) << 5;
    int wn = (wv >> 1) << 5;
    int l15 = lane & 15;
    int quad = lane >> 4;

    v4f acc00 = {0.f, 0.f, 0.f, 0.f}, acc01 = acc00, acc10 = acc00, acc11 = acc00;

    for (int k0 = 0; k0 < TT; k0 += 64) {
        __syncthreads();
        #pragma unroll
        for (int i = 0; i < 2; i++) {
            int s = (i << 8) + tid;
            int row = s >> 3, k8 = (s & 7) << 3;
            uint4 va = *(const uint4*)(A + (size_t)(m0 + row) * TT + k0 + k8);
            *(uint4*)&As[row][k8] = va;
            uint4 vb = *(const uint4*)(Bt + (size_t)(n0 + row) * TT + k0 + k8);
            *(uint4*)&Bs[row][k8] = vb;
        }
        __syncthreads();
        #pragma unroll
        for (int kq = 0; kq < 2; kq++) {
            int kc = (kq << 5) + (quad << 3);
            v8s a0 = *(const v8s*)&As[wm + l15][kc];
            v8s a1 = *(const v8s*)&As[wm + 16 + l15][kc];
            v8s b0 = *(const v8s*)&Bs[wn + l15][kc];
            v8s b1 = *(const v8s*)&Bs[wn + 16 + l15][kc];
            acc00 = __builtin_amdgcn_mfma_f32_16x16x32_bf16(a0, b0, acc00, 0, 0, 0);
            acc01 = __builtin_amdgcn_mfma_f32_16x16x32_bf16(a0, b1, acc01, 0, 0, 0);
            acc10 = __builtin_amdgcn_mfma_f32_16x16x32_bf16(a1, b0, acc10, 0, 0, 0);
            acc11 = __builtin_amdgcn_mfma_f32_16x16x32_bf16(a1, b1, acc11, 0, 0, 0);
        }
    }
    float* C = out + (size_t)b * TT * DD;
    int rbase = m0 + wm + (quad << 2);
    int cn = n0 + wn + l15;
    #pragma unroll
    for (int r = 0; r < 4; r++) {
        C[(size_t)(rbase + r) * DD + cn]           = acc00[r];
        C[(size_t)(rbase + r) * DD + cn + 16]      = acc01[r];
        C[(size_t)(rbase + 16 + r) * DD + cn]      = acc10[r];
        C[(size_t)(rbase + 16 + r) * DD + cn + 16] = acc11[r];
    }
}

extern "C" void kernel_launch(void* const* d_in, const int* in_sizes, int n_in,
                              void* d_out, int out_size, void* d_ws, size_t ws_size,
                              hipStream_t stream) {
    const float* inputs = (const float*)d_in[0];
    const float* ec     = (const float*)d_in[1];
    const float* W1     = (const float*)d_in[2];
    const float* b1     = (const float*)d_in[3];
    const float* W2     = (const float*)d_in[4];
    const float* b2     = (const float*)d_in[5];
    const float* W3     = (const float*)d_in[6];
    const float* b3     = (const float*)d_in[7];
    const float* wa_w   = (const float*)d_in[8];
    const float* wa_b   = (const float*)d_in[9];
    float* out = (float*)d_out;

    // ws (float units): E1[262144] | E2[262144] | E3[512] | at_bf (2097152 f-slots)
    //                  | xt (1048576 f-slots). Total ~14.7 MB.
    float* ws = (float*)d_ws;
    float* E1 = ws;
    float* E2 = ws + 262144;
    float* E3 = ws + 524288;
    unsigned short* at_bf = (unsigned short*)(ws + 524800);
    unsigned short* xt    = (unsigned short*)(ws + 524800 + 2097152);

    hipLaunchKernelGGL(prep_kernel, dim3(577), dim3(256), 0, stream,
                       inputs, ec, W1, b1, W2, b2, W3, b3, E1, E2, E3, xt);
    hipLaunchKernelGGL(scores_kernel, dim3(1024), dim3(256), 0, stream,
                       E1, E2, E3, wa_w, wa_b, at_bf);
    hipLaunchKernelGGL(av_mfma_kernel, dim3(DD / 64, TT / 64, BB), dim3(256), 0, stream,
                       at_bf, xt, out);
}

// Round 7
// 160.807 us; speedup vs baseline: 2.3253x; 1.0778x over previous
//
#include <hip/hip_runtime.h>
#include <hip/hip_bf16.h>

constexpr int BB = 4;
constexpr int TT = 1024;
constexpr int DD = 512;
constexpr int PP = 64;
constexpr int MM = 256;

constexpr float CSCALE = 2.8853900817779268f; // 2*log2(e)
constexpr float L2E = 1.4426950408889634f;    // log2(e)

typedef __attribute__((ext_vector_type(8))) short v8s;
typedef __attribute__((ext_vector_type(4))) float v4f;

__device__ __forceinline__ unsigned short f2bf(float f) {
    unsigned u = __builtin_bit_cast(unsigned, f);
    unsigned r = (u + 0x7fffu + ((u >> 16) & 1u)) >> 16;
    return (unsigned short)r;
}
__device__ __forceinline__ float bf2f(unsigned short h) {
    return __builtin_bit_cast(float, (unsigned)h << 16);
}
__device__ __forceinline__ void split2(float v, unsigned short& h, unsigned short& l) {
    unsigned short hh = f2bf(v);
    h = hh;
    l = f2bf(v - bf2f(hh));
}

// prep1: blocks [0,512): x tiles -> xt (bf16 transpose);
//        [512,528): W1|W2 -> WhT/WlT (bf16 hi/lo, [n][k] transposed);
//        528: ec_proj -> E3.
__global__ __launch_bounds__(256) void prep1_kernel(
    const float* __restrict__ x, const float* __restrict__ ec,
    const float* __restrict__ W1, const float* __restrict__ W2,
    const float* __restrict__ W3, const float* __restrict__ b3,
    unsigned short* __restrict__ xt,
    unsigned short* __restrict__ WhT, unsigned short* __restrict__ WlT,
    float* __restrict__ E3) {
    __shared__ float tile[64][65];
    int bid = blockIdx.x;
    int tid = threadIdx.x;
    if (bid < 512) {
        int d0 = (bid & 7) << 6;
        int u0 = ((bid >> 3) & 15) << 6;
        int b = bid >> 7;
        int c4 = (tid & 15) << 2, r = tid >> 4;
        #pragma unroll
        for (int i = 0; i < 4; i++) {
            int row = r + (i << 4);
            float4 v = *(const float4*)(x + ((size_t)b * TT + u0 + row) * DD + d0 + c4);
            tile[row][c4 + 0] = v.x;
            tile[row][c4 + 1] = v.y;
            tile[row][c4 + 2] = v.z;
            tile[row][c4 + 3] = v.w;
        }
        __syncthreads();
        int dd = tid >> 2;
        int uq = (tid & 3) << 4;
        unsigned short us[16];
        #pragma unroll
        for (int j = 0; j < 16; j++) us[j] = f2bf(tile[uq + j][dd]);
        uint4 w0, w1;
        w0.x = us[0] | ((unsigned)us[1] << 16);  w0.y = us[2] | ((unsigned)us[3] << 16);
        w0.z = us[4] | ((unsigned)us[5] << 16);  w0.w = us[6] | ((unsigned)us[7] << 16);
        w1.x = us[8] | ((unsigned)us[9] << 16);  w1.y = us[10] | ((unsigned)us[11] << 16);
        w1.z = us[12] | ((unsigned)us[13] << 16); w1.w = us[14] | ((unsigned)us[15] << 16);
        unsigned short* dst = xt + ((size_t)b * DD + d0 + dd) * TT + u0 + uq;
        *(uint4*)dst = w0;
        *(uint4*)(dst + 8) = w1;
    } else if (bid < 528) {
        // W transpose: block w covers k-slice [w*32, w*32+32), all 128 n.
        int w = bid - 512;
        int n = tid >> 1;               // 0..127
        int kb = (w << 5) + ((tid & 1) << 4);
        unsigned short hs[16], ls[16];
        #pragma unroll
        for (int kk = 0; kk < 16; kk++) {
            int k = kb + kk;
            float v = (n < 64) ? W1[k * PP + n] : W2[k * PP + (n - 64)];
            split2(v, hs[kk], ls[kk]);
        }
        uint4 a, bqq;
        a.x = hs[0] | ((unsigned)hs[1] << 16);   a.y = hs[2] | ((unsigned)hs[3] << 16);
        a.z = hs[4] | ((unsigned)hs[5] << 16);   a.w = hs[6] | ((unsigned)hs[7] << 16);
        bqq.x = hs[8] | ((unsigned)hs[9] << 16); bqq.y = hs[10] | ((unsigned)hs[11] << 16);
        bqq.z = hs[12] | ((unsigned)hs[13] << 16); bqq.w = hs[14] | ((unsigned)hs[15] << 16);
        *(uint4*)(WhT + (size_t)n * DD + kb) = a;
        *(uint4*)(WhT + (size_t)n * DD + kb + 8) = bqq;
        a.x = ls[0] | ((unsigned)ls[1] << 16);   a.y = ls[2] | ((unsigned)ls[3] << 16);
        a.z = ls[4] | ((unsigned)ls[5] << 16);   a.w = ls[6] | ((unsigned)ls[7] << 16);
        bqq.x = ls[8] | ((unsigned)ls[9] << 16); bqq.y = ls[10] | ((unsigned)ls[11] << 16);
        bqq.z = ls[12] | ((unsigned)ls[13] << 16); bqq.w = ls[14] | ((unsigned)ls[15] << 16);
        *(uint4*)(WlT + (size_t)n * DD + kb) = a;
        *(uint4*)(WlT + (size_t)n * DD + kb + 8) = bqq;
    } else {
        int b = tid >> 6, p = tid & 63;
        float a = b3[p];
        const float* e = ec + (size_t)b * MM;
        #pragma unroll 4
        for (int m = 0; m < MM; m++) a = fmaf(e[m], W3[m * PP + p], a);
        E3[b * PP + p] = __builtin_amdgcn_exp2f(a * CSCALE);
    }
}

// prep2: proj GEMM h = x (4096x512) @ [W1|W2] (512x128) via 3-term bf16-split MFMA.
// 128 blocks, tile 32m x 128n, BK=64. A staged from fp32 x with in-kernel hi/lo split
// (uint2 LDS writes); B from precomputed WhT/WlT. E1/E2 = exp2(CSCALE*(h+bias)).
__global__ __launch_bounds__(256) void prep2_kernel(
    const float* __restrict__ x,
    const unsigned short* __restrict__ WhT, const unsigned short* __restrict__ WlT,
    const float* __restrict__ b1, const float* __restrict__ b2,
    float* __restrict__ E1, float* __restrict__ E2) {
    __shared__ unsigned short AsH[32][72];
    __shared__ unsigned short AsL[32][72];
    __shared__ unsigned short BsH[128][72];
    __shared__ unsigned short BsL[128][72];   // 46 KB
    int m0 = blockIdx.x << 5;
    int tid = threadIdx.x;
    int lane = tid & 63;
    int wv = tid >> 6;
    int wn = wv << 5;
    int l15 = lane & 15;
    int quad = lane >> 4;

    v4f acc[2][2];
    #pragma unroll
    for (int mt = 0; mt < 2; mt++)
        #pragma unroll
        for (int nt = 0; nt < 2; nt++) acc[mt][nt] = (v4f){0.f, 0.f, 0.f, 0.f};

    for (int k0 = 0; k0 < DD; k0 += 64) {
        __syncthreads();
        // stage A: 32 rows x 64 k fp32 -> hi/lo. 512 float4 slots, 2 per thread.
        #pragma unroll
        for (int i = 0; i < 2; i++) {
            int s = (i << 8) + tid;
            int row = s >> 4, k4 = (s & 15) << 2;
            float4 v = *(const float4*)(x + (size_t)(m0 + row) * DD + k0 + k4);
            unsigned short h0, h1, h2, h3, l0, l1, l2, l3;
            split2(v.x, h0, l0); split2(v.y, h1, l1);
            split2(v.z, h2, l2); split2(v.w, h3, l3);
            uint2 hw, lw;
            hw.x = h0 | ((unsigned)h1 << 16); hw.y = h2 | ((unsigned)h3 << 16);
            lw.x = l0 | ((unsigned)l1 << 16); lw.y = l2 | ((unsigned)l3 << 16);
            *(uint2*)&AsH[row][k4] = hw;
            *(uint2*)&AsL[row][k4] = lw;
        }
        // stage B: 128 rows x 64 k bf16 hi/lo, 1024 uint4 slots, 4 per thread.
        #pragma unroll
        for (int i = 0; i < 4; i++) {
            int s = (i << 8) + tid;
            int row = s >> 3, k8 = (s & 7) << 3;
            *(uint4*)&BsH[row][k8] = *(const uint4*)(WhT + (size_t)row * DD + k0 + k8);
            *(uint4*)&BsL[row][k8] = *(const uint4*)(WlT + (size_t)row * DD + k0 + k8);
        }
        __syncthreads();
        #pragma unroll
        for (int kk = 0; kk < 64; kk += 32) {
            int kc = kk + (quad << 3);
            v8s aH0 = *(const v8s*)&AsH[l15][kc];
            v8s aH1 = *(const v8s*)&AsH[16 + l15][kc];
            v8s aL0 = *(const v8s*)&AsL[l15][kc];
            v8s aL1 = *(const v8s*)&AsL[16 + l15][kc];
            #pragma unroll
            for (int nt = 0; nt < 2; nt++) {
                v8s bH = *(const v8s*)&BsH[wn + (nt << 4) + l15][kc];
                v8s bL = *(const v8s*)&BsL[wn + (nt << 4) + l15][kc];
                acc[0][nt] = __builtin_amdgcn_mfma_f32_16x16x32_bf16(aH0, bH, acc[0][nt], 0, 0, 0);
                acc[0][nt] = __builtin_amdgcn_mfma_f32_16x16x32_bf16(aH0, bL, acc[0][nt], 0, 0, 0);
                acc[0][nt] = __builtin_amdgcn_mfma_f32_16x16x32_bf16(aL0, bH, acc[0][nt], 0, 0, 0);
                acc[1][nt] = __builtin_amdgcn_mfma_f32_16x16x32_bf16(aH1, bH, acc[1][nt], 0, 0, 0);
                acc[1][nt] = __builtin_amdgcn_mfma_f32_16x16x32_bf16(aH1, bL, acc[1][nt], 0, 0, 0);
                acc[1][nt] = __builtin_amdgcn_mfma_f32_16x16x32_bf16(aL1, bH, acc[1][nt], 0, 0, 0);
            }
        }
    }
    #pragma unroll
    for (int nt = 0; nt < 2; nt++) {
        int n = wn + (nt << 4) + l15;     // 0..127
        int p = n & 63;
        float bias = (n < 64) ? b1[p] : b2[p];
        float* E = (n < 64) ? E1 : E2;
        #pragma unroll
        for (int mt = 0; mt < 2; mt++) {
            int rbase = m0 + (mt << 4) + (quad << 2);
            #pragma unroll
            for (int r = 0; r < 4; r++) {
                float h = acc[mt][nt][r] + bias;
                E[(size_t)(rbase + r) * PP + p] = __builtin_amdgcn_exp2f(h * CSCALE);
            }
        }
    }
}

// scores: block = (b, 4 t rows). lane: pp=tid&7 (8 p's), uu=tid>>3 (u slot).
// Scores kept in registers (own[32]); deferred softmax; bf16 at written directly.
__global__ __launch_bounds__(256) void scores_kernel(
    const float* __restrict__ E1, const float* __restrict__ E2,
    const float* __restrict__ E3, const float* __restrict__ wa_w,
    const float* __restrict__ wa_b, unsigned short* __restrict__ at_bf) {
    __shared__ float sm[4][4];
    __shared__ float sl[4][4];
    int tid = threadIdx.x;
    int bid = blockIdx.x;
    int b = bid >> 8;
    int t0 = (bid & 255) << 2;
    int pp = tid & 7;
    int uu = tid >> 3;           // 0..31
    int p0 = pp << 3;
    int lane = tid & 63;
    int wv = tid >> 6;
    int my_i = pp & 3;
    bool pbit1 = (pp & 2) != 0;
    bool pbit0 = (pp & 1) != 0;

    float ww2[8], H[4][8];
    float base;
    {
        float4 wv0 = *(const float4*)(wa_w + p0);
        float4 wv1 = *(const float4*)(wa_w + p0 + 4);
        float s = wv0.x + wv0.y + wv0.z + wv0.w + wv1.x + wv1.y + wv1.z + wv1.w;
        s += __shfl_xor(s, 1, 64);
        s += __shfl_xor(s, 2, 64);
        s += __shfl_xor(s, 4, 64);
        base = (s + wa_b[0]) * L2E;
        ww2[0] = -2.f * L2E * wv0.x; ww2[1] = -2.f * L2E * wv0.y;
        ww2[2] = -2.f * L2E * wv0.z; ww2[3] = -2.f * L2E * wv0.w;
        ww2[4] = -2.f * L2E * wv1.x; ww2[5] = -2.f * L2E * wv1.y;
        ww2[6] = -2.f * L2E * wv1.z; ww2[7] = -2.f * L2E * wv1.w;
        float4 e3a = *(const float4*)(E3 + (b << 6) + p0);
        float4 e3b = *(const float4*)(E3 + (b << 6) + p0 + 4);
        #pragma unroll
        for (int i = 0; i < 4; i++) {
            const float* e1p = E1 + (((size_t)(b << 10) + t0 + i) << 6) + p0;
            float4 a = *(const float4*)e1p;
            float4 c = *(const float4*)(e1p + 4);
            H[i][0] = a.x * e3a.x; H[i][1] = a.y * e3a.y; H[i][2] = a.z * e3a.z; H[i][3] = a.w * e3a.w;
            H[i][4] = c.x * e3b.x; H[i][5] = c.y * e3b.y; H[i][6] = c.z * e3b.z; H[i][7] = c.w * e3b.w;
        }
    }

    float own[32];
    float mown = -1e30f;
    #pragma unroll
    for (int k = 0; k < 32; k++) {
        int u = (k << 5) + uu;
        const float* ep = E2 + (((size_t)(b << 10) + u) << 6) + p0;
        float4 e0 = *(const float4*)ep;
        float4 e1 = *(const float4*)(ep + 4);
        float ev[8] = {e0.x, e0.y, e0.z, e0.w, e1.x, e1.y, e1.z, e1.w};
        float s0 = 0.f, s1 = 0.f, s2 = 0.f, s3 = 0.f;
        #pragma unroll
        for (int j = 0; j < 8; j++) {
            s0 = fmaf(ww2[j], __builtin_amdgcn_rcpf(fmaf(H[0][j], ev[j], 1.0f)), s0);
            s1 = fmaf(ww2[j], __builtin_amdgcn_rcpf(fmaf(H[1][j], ev[j], 1.0f)), s1);
            s2 = fmaf(ww2[j], __builtin_amdgcn_rcpf(fmaf(H[2][j], ev[j], 1.0f)), s2);
            s3 = fmaf(ww2[j], __builtin_amdgcn_rcpf(fmaf(H[3][j], ev[j], 1.0f)), s3);
        }
        // 7-shfl butterfly: full-vec xor4, then select-based xor2/xor1
        s0 += __shfl_xor(s0, 4, 64);
        s1 += __shfl_xor(s1, 4, 64);
        s2 += __shfl_xor(s2, 4, 64);
        s3 += __shfl_xor(s3, 4, 64);
        float op0 = pbit1 ? s2 : s0;   // own pair (i bit1 == pp bit1)
        float op1 = pbit1 ? s3 : s1;
        float ot0 = pbit1 ? s0 : s2;   // other pair, send away
        float ot1 = pbit1 ? s1 : s3;
        op0 += __shfl_xor(ot0, 2, 64);
        op1 += __shfl_xor(ot1, 2, 64);
        float osel = pbit0 ? op1 : op0;
        float osnd = pbit0 ? op0 : op1;
        osel += __shfl_xor(osnd, 1, 64);
        float o = osel + base;
        own[k] = o;
        mown = fmaxf(mown, o);
    }
    // max across uu lanes (pp twins hold identical values)
    mown = fmaxf(mown, __shfl_xor(mown, 8, 64));
    mown = fmaxf(mown, __shfl_xor(mown, 16, 64));
    mown = fmaxf(mown, __shfl_xor(mown, 32, 64));
    if (lane < 4) sm[wv][lane] = mown;
    __syncthreads();
    float mx = fmaxf(fmaxf(sm[0][my_i], sm[1][my_i]), fmaxf(sm[2][my_i], sm[3][my_i]));

    float l = 0.f;
    #pragma unroll
    for (int k = 0; k < 32; k++) {
        float e = __builtin_amdgcn_exp2f(own[k] - mx);
        own[k] = e;
        l += e;
    }
    l += __shfl_xor(l, 8, 64);
    l += __shfl_xor(l, 16, 64);
    l += __shfl_xor(l, 32, 64);
    if (lane < 4) sl[wv][lane] = l;
    __syncthreads();
    float inv = 1.0f / (sl[0][my_i] + sl[1][my_i] + sl[2][my_i] + sl[3][my_i]);

    if (pp < 4) {
        size_t rowbase = ((size_t)((b << 10) + t0 + my_i)) << 10;
        #pragma unroll
        for (int k = 0; k < 32; k++) {
            at_bf[rowbase + (k << 5) + uu] = f2bf(own[k] * inv);
        }
    }
}

// av: out[b] = at_bf[b] (1024x1024 bf16) @ Xt[b]^T via MFMA. 64x64 tile, BK=64.
__global__ __launch_bounds__(256) void av_mfma_kernel(
    const unsigned short* __restrict__ at_bf, const unsigned short* __restrict__ xt,
    float* __restrict__ out) {
    __shared__ unsigned short As[64][72];
    __shared__ unsigned short Bs[64][72];
    int b = blockIdx.z;
    int m0 = blockIdx.y << 6;
    int n0 = blockIdx.x << 6;
    const unsigned short* A = at_bf + ((size_t)b << 20);
    const unsigned short* Bt = xt + (size_t)b * DD * TT;
    int tid = threadIdx.x;
    int lane = tid & 63;
    int wv = tid >> 6;
    int wm = (wv & 1) << 5;
    int wn = (wv >> 1) << 5;
    int l15 = lane & 15;
    int quad = lane >> 4;

    v4f acc00 = {0.f, 0.f, 0.f, 0.f}, acc01 = acc00, acc10 = acc00, acc11 = acc00;

    for (int k0 = 0; k0 < TT; k0 += 64) {
        __syncthreads();
        #pragma unroll
        for (int i = 0; i < 2; i++) {
            int s = (i << 8) + tid;
            int row = s >> 3, k8 = (s & 7) << 3;
            uint4 va = *(const uint4*)(A + (size_t)(m0 + row) * TT + k0 + k8);
            *(uint4*)&As[row][k8] = va;
            uint4 vb = *(const uint4*)(Bt + (size_t)(n0 + row) * TT + k0 + k8);
            *(uint4*)&Bs[row][k8] = vb;
        }
        __syncthreads();
        #pragma unroll
        for (int kq = 0; kq < 2; kq++) {
            int kc = (kq << 5) + (quad << 3);
            v8s a0 = *(const v8s*)&As[wm + l15][kc];
            v8s a1 = *(const v8s*)&As[wm + 16 + l15][kc];
            v8s b0 = *(const v8s*)&Bs[wn + l15][kc];
            v8s b1 = *(const v8s*)&Bs[wn + 16 + l15][kc];
            acc00 = __builtin_amdgcn_mfma_f32_16x16x32_bf16(a0, b0, acc00, 0, 0, 0);
            acc01 = __builtin_amdgcn_mfma_f32_16x16x32_bf16(a0, b1, acc01, 0, 0, 0);
            acc10 = __builtin_amdgcn_mfma_f32_16x16x32_bf16(a1, b0, acc10, 0, 0, 0);
            acc11 = __builtin_amdgcn_mfma_f32_16x16x32_bf16(a1, b1, acc11, 0, 0, 0);
        }
    }
    float* C = out + (size_t)b * TT * DD;
    int rbase = m0 + wm + (quad << 2);
    int cn = n0 + wn + l15;
    #pragma unroll
    for (int r = 0; r < 4; r++) {
        C[(size_t)(rbase + r) * DD + cn]           = acc00[r];
        C[(size_t)(rbase + r) * DD + cn + 16]      = acc01[r];
        C[(size_t)(rbase + 16 + r) * DD + cn]      = acc10[r];
        C[(size_t)(rbase + 16 + r) * DD + cn + 16] = acc11[r];
    }
}

extern "C" void kernel_launch(void* const* d_in, const int* in_sizes, int n_in,
                              void* d_out, int out_size, void* d_ws, size_t ws_size,
                              hipStream_t stream) {
    const float* inputs = (const float*)d_in[0];
    const float* ec     = (const float*)d_in[1];
    const float* W1     = (const float*)d_in[2];
    const float* b1     = (const float*)d_in[3];
    const float* W2     = (const float*)d_in[4];
    const float* b2     = (const float*)d_in[5];
    const float* W3     = (const float*)d_in[6];
    const float* b3     = (const float*)d_in[7];
    const float* wa_w   = (const float*)d_in[8];
    const float* wa_b   = (const float*)d_in[9];
    float* out = (float*)d_out;

    // ws layout (float units) — EXACTLY the R5-proven 14,682,112-byte footprint:
    //   E1[262144] | E2[262144] | E3[512] | at_bf (2097152 f) | xt (1048576 f)
    // WhT/WlT (131072 f total needed? no — 65536 f total) ALIAS the at_bf region:
    // live range WhT/WlT = prep1->prep2; at_bf written by scores strictly after.
    float* ws = (float*)d_ws;
    float* E1 = ws;
    float* E2 = ws + 262144;
    float* E3 = ws + 524288;
    unsigned short* at_bf = (unsigned short*)(ws + 524800);
    unsigned short* xt    = (unsigned short*)(ws + 524800 + 2097152);
    unsigned short* WhT   = at_bf;            // 65536 shorts
    unsigned short* WlT   = at_bf + 65536;    // 65536 shorts (both << at_bf's 4.2M)

    hipLaunchKernelGGL(prep1_kernel, dim3(529), dim3(256), 0, stream,
                       inputs, ec, W1, W2, W3, b3, xt, WhT, WlT, E3);
    hipLaunchKernelGGL(prep2_kernel, dim3(128), dim3(256), 0, stream,
                       inputs, WhT, WlT, b1, b2, E1, E2);
    hipLaunchKernelGGL(scores_kernel, dim3(1024), dim3(256), 0, stream,
                       E1, E2, E3, wa_w, wa_b, at_bf);
    hipLaunchKernelGGL(av_mfma_kernel, dim3(DD / 64, TT / 64, BB), dim3(256), 0, stream,
                       at_bf, xt, out);
}

// Round 8
// 154.689 us; speedup vs baseline: 2.4172x; 1.0395x over previous
//
#include <hip/hip_runtime.h>
#include <hip/hip_bf16.h>

constexpr int BB = 4;
constexpr int TT = 1024;
constexpr int DD = 512;
constexpr int PP = 64;
constexpr int MM = 256;

constexpr float CSCALE = 2.8853900817779268f; // 2*log2(e)
constexpr float L2E = 1.4426950408889634f;    // log2(e)

typedef __attribute__((ext_vector_type(8))) short v8s;
typedef __attribute__((ext_vector_type(4))) float v4f;
typedef unsigned int __attribute__((address_space(1))) gu32;
typedef unsigned int __attribute__((address_space(3))) su32;

__device__ __forceinline__ unsigned short f2bf(float f) {
    unsigned u = __builtin_bit_cast(unsigned, f);
    unsigned r = (u + 0x7fffu + ((u >> 16) & 1u)) >> 16;
    return (unsigned short)r;
}
__device__ __forceinline__ float bf2f(unsigned short h) {
    return __builtin_bit_cast(float, (unsigned)h << 16);
}
__device__ __forceinline__ void split2(float v, unsigned short& h, unsigned short& l) {
    unsigned short hh = f2bf(v);
    h = hh;
    l = f2bf(v - bf2f(hh));
}
__device__ __forceinline__ void gld_lds16(const void* g, void* l) {
    __builtin_amdgcn_global_load_lds((const gu32*)g, (su32*)l, 16, 0, 0);
}

// prep1: blocks [0,512): x tiles -> xt (bf16 transpose);
//        [512,528): W1|W2 -> WhT/WlT (bf16 hi/lo, [n][k] transposed);
//        528: ec_proj -> E3.
__global__ __launch_bounds__(256) void prep1_kernel(
    const float* __restrict__ x, const float* __restrict__ ec,
    const float* __restrict__ W1, const float* __restrict__ W2,
    const float* __restrict__ W3, const float* __restrict__ b3,
    unsigned short* __restrict__ xt,
    unsigned short* __restrict__ WhT, unsigned short* __restrict__ WlT,
    float* __restrict__ E3) {
    __shared__ float tile[64][65];
    int bid = blockIdx.x;
    int tid = threadIdx.x;
    if (bid < 512) {
        int d0 = (bid & 7) << 6;
        int u0 = ((bid >> 3) & 15) << 6;
        int b = bid >> 7;
        int c4 = (tid & 15) << 2, r = tid >> 4;
        #pragma unroll
        for (int i = 0; i < 4; i++) {
            int row = r + (i << 4);
            float4 v = *(const float4*)(x + ((size_t)b * TT + u0 + row) * DD + d0 + c4);
            tile[row][c4 + 0] = v.x;
            tile[row][c4 + 1] = v.y;
            tile[row][c4 + 2] = v.z;
            tile[row][c4 + 3] = v.w;
        }
        __syncthreads();
        int dd = tid >> 2;
        int uq = (tid & 3) << 4;
        unsigned short us[16];
        #pragma unroll
        for (int j = 0; j < 16; j++) us[j] = f2bf(tile[uq + j][dd]);
        uint4 w0, w1;
        w0.x = us[0] | ((unsigned)us[1] << 16);  w0.y = us[2] | ((unsigned)us[3] << 16);
        w0.z = us[4] | ((unsigned)us[5] << 16);  w0.w = us[6] | ((unsigned)us[7] << 16);
        w1.x = us[8] | ((unsigned)us[9] << 16);  w1.y = us[10] | ((unsigned)us[11] << 16);
        w1.z = us[12] | ((unsigned)us[13] << 16); w1.w = us[14] | ((unsigned)us[15] << 16);
        unsigned short* dst = xt + ((size_t)b * DD + d0 + dd) * TT + u0 + uq;
        *(uint4*)dst = w0;
        *(uint4*)(dst + 8) = w1;
    } else if (bid < 528) {
        // W transpose: block w covers k-slice [w*32, w*32+32), all 128 n.
        int w = bid - 512;
        int n = tid >> 1;               // 0..127
        int kb = (w << 5) + ((tid & 1) << 4);
        unsigned short hs[16], ls[16];
        #pragma unroll
        for (int kk = 0; kk < 16; kk++) {
            int k = kb + kk;
            float v = (n < 64) ? W1[k * PP + n] : W2[k * PP + (n - 64)];
            split2(v, hs[kk], ls[kk]);
        }
        uint4 a, bqq;
        a.x = hs[0] | ((unsigned)hs[1] << 16);   a.y = hs[2] | ((unsigned)hs[3] << 16);
        a.z = hs[4] | ((unsigned)hs[5] << 16);   a.w = hs[6] | ((unsigned)hs[7] << 16);
        bqq.x = hs[8] | ((unsigned)hs[9] << 16); bqq.y = hs[10] | ((unsigned)hs[11] << 16);
        bqq.z = hs[12] | ((unsigned)hs[13] << 16); bqq.w = hs[14] | ((unsigned)hs[15] << 16);
        *(uint4*)(WhT + (size_t)n * DD + kb) = a;
        *(uint4*)(WhT + (size_t)n * DD + kb + 8) = bqq;
        a.x = ls[0] | ((unsigned)ls[1] << 16);   a.y = ls[2] | ((unsigned)ls[3] << 16);
        a.z = ls[4] | ((unsigned)ls[5] << 16);   a.w = ls[6] | ((unsigned)ls[7] << 16);
        bqq.x = ls[8] | ((unsigned)ls[9] << 16); bqq.y = ls[10] | ((unsigned)ls[11] << 16);
        bqq.z = ls[12] | ((unsigned)ls[13] << 16); bqq.w = ls[14] | ((unsigned)ls[15] << 16);
        *(uint4*)(WlT + (size_t)n * DD + kb) = a;
        *(uint4*)(WlT + (size_t)n * DD + kb + 8) = bqq;
    } else {
        int b = tid >> 6, p = tid & 63;
        float a = b3[p];
        const float* e = ec + (size_t)b * MM;
        #pragma unroll 4
        for (int m = 0; m < MM; m++) a = fmaf(e[m], W3[m * PP + p], a);
        E3[b * PP + p] = __builtin_amdgcn_exp2f(a * CSCALE);
    }
}

// prep2: proj GEMM h = x (4096x512) @ [W1|W2] (512x128) via 3-term bf16-split MFMA.
// 256 blocks, tile 16m x 128n, BK=64. E1/E2 = exp2(CSCALE*(h+bias)).
__global__ __launch_bounds__(256) void prep2_kernel(
    const float* __restrict__ x,
    const unsigned short* __restrict__ WhT, const unsigned short* __restrict__ WlT,
    const float* __restrict__ b1, const float* __restrict__ b2,
    float* __restrict__ E1, float* __restrict__ E2) {
    __shared__ unsigned short AsH[16][72];
    __shared__ unsigned short AsL[16][72];
    __shared__ unsigned short BsH[128][72];
    __shared__ unsigned short BsL[128][72];   // 41.6 KB
    int m0 = blockIdx.x << 4;
    int tid = threadIdx.x;
    int lane = tid & 63;
    int wv = tid >> 6;
    int wn = wv << 5;
    int l15 = lane & 15;
    int quad = lane >> 4;

    v4f acc[2];
    acc[0] = (v4f){0.f, 0.f, 0.f, 0.f};
    acc[1] = acc[0];

    for (int k0 = 0; k0 < DD; k0 += 64) {
        __syncthreads();
        // stage A: 16 rows x 64 k fp32 -> hi/lo. 256 float4 slots, 1 per thread.
        {
            int row = tid >> 4, k4 = (tid & 15) << 2;
            float4 v = *(const float4*)(x + (size_t)(m0 + row) * DD + k0 + k4);
            unsigned short h0, h1, h2, h3, l0, l1, l2, l3;
            split2(v.x, h0, l0); split2(v.y, h1, l1);
            split2(v.z, h2, l2); split2(v.w, h3, l3);
            uint2 hw, lw;
            hw.x = h0 | ((unsigned)h1 << 16); hw.y = h2 | ((unsigned)h3 << 16);
            lw.x = l0 | ((unsigned)l1 << 16); lw.y = l2 | ((unsigned)l3 << 16);
            *(uint2*)&AsH[row][k4] = hw;
            *(uint2*)&AsL[row][k4] = lw;
        }
        // stage B: 128 rows x 64 k bf16 hi/lo, 1024 uint4 slots, 4 per thread.
        #pragma unroll
        for (int i = 0; i < 4; i++) {
            int s = (i << 8) + tid;
            int row = s >> 3, k8 = (s & 7) << 3;
            *(uint4*)&BsH[row][k8] = *(const uint4*)(WhT + (size_t)row * DD + k0 + k8);
            *(uint4*)&BsL[row][k8] = *(const uint4*)(WlT + (size_t)row * DD + k0 + k8);
        }
        __syncthreads();
        #pragma unroll
        for (int kk = 0; kk < 64; kk += 32) {
            int kc = kk + (quad << 3);
            v8s aH0 = *(const v8s*)&AsH[l15][kc];
            v8s aL0 = *(const v8s*)&AsL[l15][kc];
            #pragma unroll
            for (int nt = 0; nt < 2; nt++) {
                v8s bH = *(const v8s*)&BsH[wn + (nt << 4) + l15][kc];
                v8s bL = *(const v8s*)&BsL[wn + (nt << 4) + l15][kc];
                acc[nt] = __builtin_amdgcn_mfma_f32_16x16x32_bf16(aH0, bH, acc[nt], 0, 0, 0);
                acc[nt] = __builtin_amdgcn_mfma_f32_16x16x32_bf16(aH0, bL, acc[nt], 0, 0, 0);
                acc[nt] = __builtin_amdgcn_mfma_f32_16x16x32_bf16(aL0, bH, acc[nt], 0, 0, 0);
            }
        }
    }
    #pragma unroll
    for (int nt = 0; nt < 2; nt++) {
        int n = wn + (nt << 4) + l15;     // 0..127
        int p = n & 63;
        float bias = (n < 64) ? b1[p] : b2[p];
        float* E = (n < 64) ? E1 : E2;
        int rbase = m0 + (quad << 2);
        #pragma unroll
        for (int r = 0; r < 4; r++) {
            float h = acc[nt][r] + bias;
            E[(size_t)(rbase + r) * PP + p] = __builtin_amdgcn_exp2f(h * CSCALE);
        }
    }
}

// scores: block = (b, 4 t rows). lane: pp=tid&7 (8 p's), uu=tid>>3 (u slot).
// Scores kept in registers (own[32]); deferred softmax; bf16 at written directly.
__global__ __launch_bounds__(256) void scores_kernel(
    const float* __restrict__ E1, const float* __restrict__ E2,
    const float* __restrict__ E3, const float* __restrict__ wa_w,
    const float* __restrict__ wa_b, unsigned short* __restrict__ at_bf) {
    __shared__ float sm[4][4];
    __shared__ float sl[4][4];
    int tid = threadIdx.x;
    int bid = blockIdx.x;
    int b = bid >> 8;
    int t0 = (bid & 255) << 2;
    int pp = tid & 7;
    int uu = tid >> 3;           // 0..31
    int p0 = pp << 3;
    int lane = tid & 63;
    int wv = tid >> 6;
    int my_i = pp & 3;
    bool pbit1 = (pp & 2) != 0;
    bool pbit0 = (pp & 1) != 0;

    float ww2[8], H[4][8];
    float base;
    {
        float4 wv0 = *(const float4*)(wa_w + p0);
        float4 wv1 = *(const float4*)(wa_w + p0 + 4);
        float s = wv0.x + wv0.y + wv0.z + wv0.w + wv1.x + wv1.y + wv1.z + wv1.w;
        s += __shfl_xor(s, 1, 64);
        s += __shfl_xor(s, 2, 64);
        s += __shfl_xor(s, 4, 64);
        base = (s + wa_b[0]) * L2E;
        ww2[0] = -2.f * L2E * wv0.x; ww2[1] = -2.f * L2E * wv0.y;
        ww2[2] = -2.f * L2E * wv0.z; ww2[3] = -2.f * L2E * wv0.w;
        ww2[4] = -2.f * L2E * wv1.x; ww2[5] = -2.f * L2E * wv1.y;
        ww2[6] = -2.f * L2E * wv1.z; ww2[7] = -2.f * L2E * wv1.w;
        float4 e3a = *(const float4*)(E3 + (b << 6) + p0);
        float4 e3b = *(const float4*)(E3 + (b << 6) + p0 + 4);
        #pragma unroll
        for (int i = 0; i < 4; i++) {
            const float* e1p = E1 + (((size_t)(b << 10) + t0 + i) << 6) + p0;
            float4 a = *(const float4*)e1p;
            float4 c = *(const float4*)(e1p + 4);
            H[i][0] = a.x * e3a.x; H[i][1] = a.y * e3a.y; H[i][2] = a.z * e3a.z; H[i][3] = a.w * e3a.w;
            H[i][4] = c.x * e3b.x; H[i][5] = c.y * e3b.y; H[i][6] = c.z * e3b.z; H[i][7] = c.w * e3b.w;
        }
    }

    float own[32];
    float mown = -1e30f;
    #pragma unroll
    for (int k = 0; k < 32; k++) {
        int u = (k << 5) + uu;
        const float* ep = E2 + (((size_t)(b << 10) + u) << 6) + p0;
        float4 e0 = *(const float4*)ep;
        float4 e1 = *(const float4*)(ep + 4);
        float ev[8] = {e0.x, e0.y, e0.z, e0.w, e1.x, e1.y, e1.z, e1.w};
        float s0 = 0.f, s1 = 0.f, s2 = 0.f, s3 = 0.f;
        #pragma unroll
        for (int j = 0; j < 8; j++) {
            s0 = fmaf(ww2[j], __builtin_amdgcn_rcpf(fmaf(H[0][j], ev[j], 1.0f)), s0);
            s1 = fmaf(ww2[j], __builtin_amdgcn_rcpf(fmaf(H[1][j], ev[j], 1.0f)), s1);
            s2 = fmaf(ww2[j], __builtin_amdgcn_rcpf(fmaf(H[2][j], ev[j], 1.0f)), s2);
            s3 = fmaf(ww2[j], __builtin_amdgcn_rcpf(fmaf(H[3][j], ev[j], 1.0f)), s3);
        }
        // 7-shfl butterfly: full-vec xor4, then select-based xor2/xor1
        s0 += __shfl_xor(s0, 4, 64);
        s1 += __shfl_xor(s1, 4, 64);
        s2 += __shfl_xor(s2, 4, 64);
        s3 += __shfl_xor(s3, 4, 64);
        float op0 = pbit1 ? s2 : s0;   // own pair (i bit1 == pp bit1)
        float op1 = pbit1 ? s3 : s1;
        float ot0 = pbit1 ? s0 : s2;   // other pair, send away
        float ot1 = pbit1 ? s1 : s3;
        op0 += __shfl_xor(ot0, 2, 64);
        op1 += __shfl_xor(ot1, 2, 64);
        float osel = pbit0 ? op1 : op0;
        float osnd = pbit0 ? op0 : op1;
        osel += __shfl_xor(osnd, 1, 64);
        float o = osel + base;
        own[k] = o;
        mown = fmaxf(mown, o);
    }
    // max across uu lanes (pp twins hold identical values)
    mown = fmaxf(mown, __shfl_xor(mown, 8, 64));
    mown = fmaxf(mown, __shfl_xor(mown, 16, 64));
    mown = fmaxf(mown, __shfl_xor(mown, 32, 64));
    if (lane < 4) sm[wv][lane] = mown;
    __syncthreads();
    float mx = fmaxf(fmaxf(sm[0][my_i], sm[1][my_i]), fmaxf(sm[2][my_i], sm[3][my_i]));

    float l = 0.f;
    #pragma unroll
    for (int k = 0; k < 32; k++) {
        float e = __builtin_amdgcn_exp2f(own[k] - mx);
        own[k] = e;
        l += e;
    }
    l += __shfl_xor(l, 8, 64);
    l += __shfl_xor(l, 16, 64);
    l += __shfl_xor(l, 32, 64);
    if (lane < 4) sl[wv][lane] = l;
    __syncthreads();
    float inv = 1.0f / (sl[0][my_i] + sl[1][my_i] + sl[2][my_i] + sl[3][my_i]);

    if (pp < 4) {
        size_t rowbase = ((size_t)((b << 10) + t0 + my_i)) << 10;
        #pragma unroll
        for (int k = 0; k < 32; k++) {
            at_bf[rowbase + (k << 5) + uu] = f2bf(own[k] * inv);
        }
    }
}

// av: out[b] = at_bf[b] (1024x1024 bf16) @ Xt[b]^T via MFMA. 64x64 tile, BK=64.
// Staging via global_load_lds width=16 (DMA, no ds_write pipe cost). LDS tiles
// unpadded [64][64]; column chunks XOR-swizzled by (row&7) at the GLOBAL source
// so fragment ds_read_b128 is 2-way (free) bank access.
__global__ __launch_bounds__(256) void av_mfma_kernel(
    const unsigned short* __restrict__ at_bf, const unsigned short* __restrict__ xt,
    float* __restrict__ out) {
    __shared__ unsigned short As[64 * 64];  // 8 KB
    __shared__ unsigned short Bs[64 * 64];  // 8 KB
    int b = blockIdx.z;
    int m0 = blockIdx.y << 6;
    int n0 = blockIdx.x << 6;
    const unsigned short* A = at_bf + ((size_t)b << 20);
    const unsigned short* Bt = xt + (size_t)b * DD * TT;
    int tid = threadIdx.x;
    int lane = tid & 63;
    int wv = tid >> 6;
    int wm = (wv & 1) << 5;
    int wn = (wv >> 1) << 5;
    int l15 = lane & 15;
    int quad = lane >> 4;

    int sr = lane >> 3;           // 0..7 relative row within wave-instr
    int scg = (lane & 7) ^ sr;    // swizzled source chunk

    v4f acc00 = {0.f, 0.f, 0.f, 0.f}, acc01 = acc00, acc10 = acc00, acc11 = acc00;

    for (int k0 = 0; k0 < TT; k0 += 64) {
        __syncthreads();
        #pragma unroll
        for (int t = 0; t < 2; t++) {
            int r0 = (wv << 4) + (t << 3);    // wave-uniform row base, 8 rows/instr
            int row = r0 + sr;
            gld_lds16(A + (size_t)(m0 + row) * TT + k0 + (scg << 3), &As[r0 << 6]);
            gld_lds16(Bt + (size_t)(n0 + row) * TT + k0 + (scg << 3), &Bs[r0 << 6]);
        }
        __syncthreads();
        #pragma unroll
        for (int kq = 0; kq < 2; kq++) {
            int c = (kq << 2) + quad;
            int swz = (c ^ (l15 & 7)) << 3;
            v8s a0 = *(const v8s*)&As[((wm + l15) << 6) + swz];
            v8s a1 = *(const v8s*)&As[((wm + 16 + l15) << 6) + swz];
            v8s b0 = *(const v8s*)&Bs[((wn + l15) << 6) + swz];
            v8s b1 = *(const v8s*)&Bs[((wn + 16 + l15) << 6) + swz];
            acc00 = __builtin_amdgcn_mfma_f32_16x16x32_bf16(a0, b0, acc00, 0, 0, 0);
            acc01 = __builtin_amdgcn_mfma_f32_16x16x32_bf16(a0, b1, acc01, 0, 0, 0);
            acc10 = __builtin_amdgcn_mfma_f32_16x16x32_bf16(a1, b0, acc10, 0, 0, 0);
            acc11 = __builtin_amdgcn_mfma_f32_16x16x32_bf16(a1, b1, acc11, 0, 0, 0);
        }
    }
    float* C = out + (size_t)b * TT * DD;
    int rbase = m0 + wm + (quad << 2);
    int cn = n0 + wn + l15;
    #pragma unroll
    for (int r = 0; r < 4; r++) {
        C[(size_t)(rbase + r) * DD + cn]           = acc00[r];
        C[(size_t)(rbase + r) * DD + cn + 16]      = acc01[r];
        C[(size_t)(rbase + 16 + r) * DD + cn]      = acc10[r];
        C[(size_t)(rbase + 16 + r) * DD + cn + 16] = acc11[r];
    }
}

extern "C" void kernel_launch(void* const* d_in, const int* in_sizes, int n_in,
                              void* d_out, int out_size, void* d_ws, size_t ws_size,
                              hipStream_t stream) {
    const float* inputs = (const float*)d_in[0];
    const float* ec     = (const float*)d_in[1];
    const float* W1     = (const float*)d_in[2];
    const float* b1     = (const float*)d_in[3];
    const float* W2     = (const float*)d_in[4];
    const float* b2     = (const float*)d_in[5];
    const float* W3     = (const float*)d_in[6];
    const float* b3     = (const float*)d_in[7];
    const float* wa_w   = (const float*)d_in[8];
    const float* wa_b   = (const float*)d_in[9];
    float* out = (float*)d_out;

    // ws layout (float units) — R5/R7-proven 14,682,112-byte footprint:
    //   E1[262144] | E2[262144] | E3[512] | at_bf (2097152 f) | xt (1048576 f)
    // WhT/WlT alias the front of at_bf (live range prep1->prep2 only).
    float* ws = (float*)d_ws;
    float* E1 = ws;
    float* E2 = ws + 262144;
    float* E3 = ws + 524288;
    unsigned short* at_bf = (unsigned short*)(ws + 524800);
    unsigned short* xt    = (unsigned short*)(ws + 524800 + 2097152);
    unsigned short* WhT   = at_bf;            // 65536 shorts
    unsigned short* WlT   = at_bf + 65536;    // 65536 shorts

    hipLaunchKernelGGL(prep1_kernel, dim3(529), dim3(256), 0, stream,
                       inputs, ec, W1, W2, W3, b3, xt, WhT, WlT, E3);
    hipLaunchKernelGGL(prep2_kernel, dim3(256), dim3(256), 0, stream,
                       inputs, WhT, WlT, b1, b2, E1, E2);
    hipLaunchKernelGGL(scores_kernel, dim3(1024), dim3(256), 0, stream,
                       E1, E2, E3, wa_w, wa_b, at_bf);
    hipLaunchKernelGGL(av_mfma_kernel, dim3(DD / 64, TT / 64, BB), dim3(256), 0, stream,
                       at_bf, xt, out);
}